// Round 5
// baseline (418.693 us; speedup 1.0000x reference)
//
#include <hip/hip_runtime.h>

// Problem constants (from reference setup_inputs)
constexpr int NN = 50000;   // nodes
constexpr int H  = 128;     // hidden
constexpr int F  = 256;     // input features
constexpr int C  = 40;      // classes

// graph-prepass partitioning
constexpr int RSZ = 4096;                 // nodes per range (LDS histogram size)
constexpr int NR  = (NN + RSZ - 1) / RSZ; // 13 ranges
constexpr int BR  = 20;                   // edge chunks per range

typedef short bf16x8 __attribute__((ext_vector_type(8)));
typedef short s16x4  __attribute__((ext_vector_type(4)));
typedef float f32x4  __attribute__((ext_vector_type(4)));

__device__ inline unsigned short f2bf(float f) {          // RNE fp32 -> bf16
    unsigned u = __float_as_uint(f);
    u += 0x7fff + ((u >> 16) & 1);
    return (unsigned short)(u >> 16);
}
__device__ inline float bf2f(unsigned short s) {
    return __uint_as_float(((unsigned)s) << 16);
}

// ------------------------------------------------ graph prepass (atomic-free global)
// Phase A: per-(range, chunk) LDS histograms of src (out-deg) and dst (in-deg).
__global__ __launch_bounds__(256) void hist_partial(
        const int* __restrict__ src, const int* __restrict__ dst,
        int* __restrict__ p_out, int* __restrict__ p_in, int E) {
    __shared__ int h_out[RSZ];
    __shared__ int h_in[RSZ];
    const int r = blockIdx.x;       // node range
    const int b = blockIdx.y;       // edge chunk
    for (int i = threadIdx.x; i < RSZ; i += 256) { h_out[i] = 0; h_in[i] = 0; }
    __syncthreads();
    const int base = r * RSZ;
    const int CE = (E + BR - 1) / BR;
    const int e0 = b * CE, e1 = min(E, e0 + CE);
    for (int e = e0 + threadIdx.x; e < e1; e += 256) {
        int s = src[e], d = dst[e];
        unsigned so = (unsigned)(s - base);
        unsigned dо = (unsigned)(d - base);
        if (so < (unsigned)RSZ) atomicAdd(&h_out[so], 1);
        if (dо < (unsigned)RSZ) atomicAdd(&h_in[dо], 1);
    }
    __syncthreads();
    const long po = ((long)r * BR + b) * RSZ;
    for (int i = threadIdx.x; i < RSZ; i += 256) {
        p_out[po + i] = h_out[i];
        p_in[po + i]  = h_in[i];
    }
}

// Phase B: per-node merge of partials -> cnt_in, rs_out, rs_in;
// converts p_in in-place to exclusive prefix over chunks (per-chunk CSR cursor base).
__global__ __launch_bounds__(256) void merge_deg(
        const int* __restrict__ p_out, int* __restrict__ p_in,
        int* __restrict__ cnt_in, float* __restrict__ rs_out, float* __restrict__ rs_in,
        int n) {
    const int i = blockIdx.x * 256 + threadIdx.x;
    if (i >= n) return;
    const int r = i / RSZ, off = i % RSZ;
    const long pb = (long)r * BR * RSZ + off;
    int so = 0, si = 0;
#pragma unroll 4
    for (int b = 0; b < BR; b++) {
        so += p_out[pb + (long)b * RSZ];
        int v = p_in[pb + (long)b * RSZ];
        p_in[pb + (long)b * RSZ] = si;      // exclusive prefix
        si += v;
    }
    cnt_in[i] = si;
    rs_out[i] = rsqrtf((float)max(so, 1));
    rs_in[i]  = rsqrtf((float)max(si, 1));
}

// Phase D (after scan): CSR fill with LDS cursors — no global atomics.
__global__ __launch_bounds__(256) void fill_csr_part(
        const int* __restrict__ src, const int* __restrict__ dst,
        const int* __restrict__ row_start, const int* __restrict__ p_in,
        int* __restrict__ csr_src, int E, int n_nodes) {
    __shared__ int cur[RSZ];
    const int r = blockIdx.x;
    const int b = blockIdx.y;
    const int base = r * RSZ;
    const long po = ((long)r * BR + b) * RSZ;
    for (int i = threadIdx.x; i < RSZ; i += 256) {
        int node = base + i;
        cur[i] = (node < n_nodes ? row_start[node] : 0) + p_in[po + i];
    }
    __syncthreads();
    const int CE = (E + BR - 1) / BR;
    const int e0 = b * CE, e1 = min(E, e0 + CE);
    for (int e = e0 + threadIdx.x; e < e1; e += 256) {
        int d = dst[e];
        unsigned dof = (unsigned)(d - base);
        if (dof < (unsigned)RSZ) {
            int pos = atomicAdd(&cur[dof], 1);   // LDS atomic (fast)
            csr_src[pos] = src[e];
        }
    }
}

// ------------------------------------------------ parallel exclusive scan
__global__ __launch_bounds__(256) void scan_partial(
        const int* __restrict__ cnt, int* __restrict__ excl,
        int* __restrict__ block_sums, int n) {
    __shared__ int sh[256];
    const int t = threadIdx.x;
    const int i = blockIdx.x * 256 + t;
    const int v = (i < n) ? cnt[i] : 0;
    sh[t] = v;
    __syncthreads();
#pragma unroll
    for (int off = 1; off < 256; off <<= 1) {
        int u = (t >= off) ? sh[t - off] : 0;
        __syncthreads();
        sh[t] += u;
        __syncthreads();
    }
    if (i < n) excl[i] = sh[t] - v;
    if (t == 255) block_sums[blockIdx.x] = sh[255];
}

__global__ __launch_bounds__(256) void scan_sums(int* __restrict__ block_sums, int nb) {
    __shared__ int sh[256];
    const int t = threadIdx.x;
    const int v = (t < nb) ? block_sums[t] : 0;
    sh[t] = v;
    __syncthreads();
#pragma unroll
    for (int off = 1; off < 256; off <<= 1) {
        int u = (t >= off) ? sh[t - off] : 0;
        __syncthreads();
        sh[t] += u;
        __syncthreads();
    }
    if (t < nb) block_sums[t] = sh[t] - v;
}

__global__ __launch_bounds__(256) void scan_add(
        int* __restrict__ row_start, const int* __restrict__ block_sums, int n) {
    const int i = blockIdx.x * 256 + threadIdx.x;
    if (i < n) row_start[i] += block_sums[blockIdx.x];
}

// ------------------------------------------------ weight prep: transpose + hi/lo split
__global__ void prep_Bt(const float* __restrict__ W,
                        unsigned short* __restrict__ Bth, unsigned short* __restrict__ Btl,
                        int K, int N, int NP) {
    int i = blockIdx.x * blockDim.x + threadIdx.x;
    if (i >= NP * K) return;
    int n = i / K, k = i % K;
    float v = (n < N) ? W[(long)k * N + n] : 0.f;
    unsigned short hh = f2bf(v);
    unsigned short ll = f2bf(v - bf2f(hh));
    Bth[(long)n * K + k] = hh;
    Btl[(long)n * K + k] = ll;
}

// ------------------------------------------------ MFMA split-bf16 GEMM
// C = A(fp32,[M,K]) @ B(fp32,[K,Nout]) via hi/lo bf16 split (3 MFMA products).
// MODE 0: outf = acc + bias[gc]   (gc < Nout mask);  MODE 1: outh = bf16(acc*row_scale)
template<int MODE, int BN>
__global__ __launch_bounds__(256) void mfma_gemm(
        const float* __restrict__ A,
        const unsigned short* __restrict__ Bth, const unsigned short* __restrict__ Btl,
        const float* __restrict__ bias, const float* __restrict__ row_scale,
        float* __restrict__ outf, unsigned short* __restrict__ outh,
        int M, int Nout, int K) {
    constexpr int NT = BN / 64;
    __shared__ unsigned short As_h[4 * 65 * 8];
    __shared__ unsigned short As_l[4 * 65 * 8];
    __shared__ unsigned short Bs_h[4 * (BN + 1) * 8];
    __shared__ unsigned short Bs_l[4 * (BN + 1) * 8];

    const int tid  = threadIdx.x;
    const int wave = tid >> 6;
    const int lane = tid & 63;
    const int quad = lane >> 4;
    const int lr   = lane & 15;
    const int row0 = blockIdx.y * 64;
    const int wn0  = wave * (BN / 4);

    f32x4 acc[4][NT];
#pragma unroll
    for (int mt = 0; mt < 4; mt++)
#pragma unroll
        for (int nt = 0; nt < NT; nt++)
            acc[mt][nt] = (f32x4){0.f, 0.f, 0.f, 0.f};

    for (int k0 = 0; k0 < K; k0 += 32) {
#pragma unroll
        for (int r = 0; r < 2; r++) {
            int c   = tid + 256 * r;
            int row = c >> 3;
            int k4f = c & 7;
            int gr  = row0 + row;
            float4 v = make_float4(0.f, 0.f, 0.f, 0.f);
            if (gr < M) v = *(const float4*)&A[(long)gr * K + k0 + k4f * 4];
            unsigned short h0 = f2bf(v.x), h1 = f2bf(v.y), h2 = f2bf(v.z), h3 = f2bf(v.w);
            unsigned short l0 = f2bf(v.x - bf2f(h0));
            unsigned short l1 = f2bf(v.y - bf2f(h1));
            unsigned short l2 = f2bf(v.z - bf2f(h2));
            unsigned short l3 = f2bf(v.w - bf2f(h3));
            int base = (k4f >> 1) * 520 + row * 8 + (k4f & 1) * 4;
            s16x4 hv; hv[0] = (short)h0; hv[1] = (short)h1; hv[2] = (short)h2; hv[3] = (short)h3;
            s16x4 lv; lv[0] = (short)l0; lv[1] = (short)l1; lv[2] = (short)l2; lv[3] = (short)l3;
            *(s16x4*)&As_h[base] = hv;
            *(s16x4*)&As_l[base] = lv;
        }
        for (int c = tid; c < BN * 4; c += 256) {
            int n  = c >> 2;
            int k4 = c & 3;
            long off = (long)n * K + k0 + k4 * 8;
            uint4 vh = *(const uint4*)&Bth[off];
            uint4 vl = *(const uint4*)&Btl[off];
            int bbase = k4 * (BN + 1) * 8 + n * 8;
            *(uint4*)&Bs_h[bbase] = vh;
            *(uint4*)&Bs_l[bbase] = vl;
        }
        __syncthreads();

        bf16x8 ah[4], al[4], bh[NT], bl[NT];
#pragma unroll
        for (int mt = 0; mt < 4; mt++) {
            int ab = quad * 520 + (mt * 16 + lr) * 8;
            ah[mt] = *(const bf16x8*)&As_h[ab];
            al[mt] = *(const bf16x8*)&As_l[ab];
        }
#pragma unroll
        for (int nt = 0; nt < NT; nt++) {
            int bb = quad * (BN + 1) * 8 + (wn0 + nt * 16 + lr) * 8;
            bh[nt] = *(const bf16x8*)&Bs_h[bb];
            bl[nt] = *(const bf16x8*)&Bs_l[bb];
        }
#pragma unroll
        for (int mt = 0; mt < 4; mt++)
#pragma unroll
            for (int nt = 0; nt < NT; nt++) {
                acc[mt][nt] = __builtin_amdgcn_mfma_f32_16x16x32_bf16(ah[mt], bh[nt], acc[mt][nt], 0, 0, 0);
                acc[mt][nt] = __builtin_amdgcn_mfma_f32_16x16x32_bf16(al[mt], bh[nt], acc[mt][nt], 0, 0, 0);
                acc[mt][nt] = __builtin_amdgcn_mfma_f32_16x16x32_bf16(ah[mt], bl[nt], acc[mt][nt], 0, 0, 0);
            }
        __syncthreads();
    }

#pragma unroll
    for (int mt = 0; mt < 4; mt++) {
#pragma unroll
        for (int nt = 0; nt < NT; nt++) {
            int gc = wn0 + nt * 16 + lr;
#pragma unroll
            for (int r = 0; r < 4; r++) {
                int gr = row0 + mt * 16 + quad * 4 + r;
                if (gr >= M) continue;
                float v = acc[mt][nt][r];
                if (MODE == 0) {
                    if (gc < Nout) outf[(long)gr * Nout + gc] = v + bias[gc];
                } else {
                    v *= row_scale[gr];
                    outh[(long)gr * Nout + gc] = f2bf(v);
                }
            }
        }
    }
}

// ---------------------------------------------------------------- aggregation (bf16 h)
__global__ __launch_bounds__(256) void aggregate_bf16(
        const unsigned int* __restrict__ h, const int* __restrict__ csr_src,
        const int* __restrict__ row_start, const int* __restrict__ cnt_in,
        const float* __restrict__ rs_in, const float* __restrict__ bias,
        float* __restrict__ out, int nodes) {
    const int wave = threadIdx.x >> 6;
    const int lane = threadIdx.x & 63;
    const int v = blockIdx.x * 4 + wave;
    if (v >= nodes) return;
    const int s0  = row_start[v];
    const int cnt = cnt_in[v];
    float ax = 0.f, ay = 0.f;
    int i = 0;
    for (; i + 4 <= cnt; i += 4) {
        int sa = csr_src[s0 + i];
        int sb = csr_src[s0 + i + 1];
        int sc = csr_src[s0 + i + 2];
        int sd = csr_src[s0 + i + 3];
        unsigned ua = h[(long)sa * 64 + lane];
        unsigned ub = h[(long)sb * 64 + lane];
        unsigned uc = h[(long)sc * 64 + lane];
        unsigned ud = h[(long)sd * 64 + lane];
        ax += __uint_as_float(ua << 16) + __uint_as_float(ub << 16)
            + __uint_as_float(uc << 16) + __uint_as_float(ud << 16);
        ay += __uint_as_float(ua & 0xffff0000u) + __uint_as_float(ub & 0xffff0000u)
            + __uint_as_float(uc & 0xffff0000u) + __uint_as_float(ud & 0xffff0000u);
    }
    for (; i < cnt; i++) {
        int s = csr_src[s0 + i];
        unsigned u = h[(long)s * 64 + lane];
        ax += __uint_as_float(u << 16);
        ay += __uint_as_float(u & 0xffff0000u);
    }
    const float rs = rs_in[v];
    const float2 bb = ((const float2*)bias)[lane];
    float2 o;
    o.x = fmaxf(ax * rs + bb.x, 0.f);
    o.y = fmaxf(ay * rs + bb.y, 0.f);
    ((float2*)out)[(long)v * 64 + lane] = o;
}

// ---------------------------------------------------------------- launch
extern "C" void kernel_launch(void* const* d_in, const int* in_sizes, int n_in,
                              void* d_out, int out_size, void* d_ws, size_t ws_size,
                              hipStream_t stream) {
    const float* n_feats = (const float*)d_in[0];
    const int*   src     = (const int*)d_in[1];
    const int*   dst     = (const int*)d_in[2];
    const float* Wp      = (const float*)d_in[3];
    const float* bp      = (const float*)d_in[4];
    const float* W1      = (const float*)d_in[5];
    const float* b1      = (const float*)d_in[6];
    const float* W2      = (const float*)d_in[7];
    const float* b2      = (const float*)d_in[8];
    const float* Wc      = (const float*)d_in[9];
    const float* bc      = (const float*)d_in[10];
    float* out = (float*)d_out;
    const int E = in_sizes[1];

    // workspace layout
    char* ws = (char*)d_ws;
    float*          xbuf  = (float*)ws;                             // NN*128 fp32
    unsigned short* hbuf  = (unsigned short*)(xbuf + (long)NN * H); // NN*128 bf16
    unsigned short* bt_ph = hbuf + (long)NN * H;                    // 128*256
    unsigned short* bt_pl = bt_ph + 128 * 256;
    unsigned short* bt_1h = bt_pl + 128 * 256;                      // 128*128
    unsigned short* bt_1l = bt_1h + 128 * 128;
    unsigned short* bt_2h = bt_1l + 128 * 128;
    unsigned short* bt_2l = bt_2h + 128 * 128;
    unsigned short* bt_ch = bt_2l + 128 * 128;                      // 64*128
    unsigned short* bt_cl = bt_ch + 64 * 128;
    int*   cnt_in     = (int*)(bt_cl + 64 * 128);                   // N
    int*   row_start  = cnt_in + NN;                                // N
    float* rs_out     = (float*)(row_start + NN);                   // N
    float* rs_in      = rs_out + NN;                                // N
    int*   block_sums = (int*)(rs_in + NN);                         // 256
    int*   csr_src    = block_sums + 256;                           // E
    int*   p_out      = csr_src + E;                                // NR*BR*RSZ
    int*   p_in       = p_out + (long)NR * BR * RSZ;                // NR*BR*RSZ

    const int TB = 256;
    const int NB = (NN + 255) / 256;
    const dim3 ghist(NR, BR);
    // graph prepass (atomic-free at device scope)
    hist_partial<<<ghist, 256, 0, stream>>>(src, dst, p_out, p_in, E);
    merge_deg<<<(NN + TB - 1) / TB, TB, 0, stream>>>(p_out, p_in, cnt_in, rs_out, rs_in, NN);
    scan_partial<<<NB, 256, 0, stream>>>(cnt_in, row_start, block_sums, NN);
    scan_sums<<<1, 256, 0, stream>>>(block_sums, NB);
    scan_add<<<NB, 256, 0, stream>>>(row_start, block_sums, NN);
    fill_csr_part<<<ghist, 256, 0, stream>>>(src, dst, row_start, p_in, csr_src, E, NN);
    // weight prep (transpose + hi/lo split)
    prep_Bt<<<(128 * F + TB - 1) / TB, TB, 0, stream>>>(Wp, bt_ph, bt_pl, F, H, 128);
    prep_Bt<<<(128 * H + TB - 1) / TB, TB, 0, stream>>>(W1, bt_1h, bt_1l, H, H, 128);
    prep_Bt<<<(128 * H + TB - 1) / TB, TB, 0, stream>>>(W2, bt_2h, bt_2l, H, H, 128);
    prep_Bt<<<(64 * H + TB - 1) / TB, TB, 0, stream>>>(Wc, bt_ch, bt_cl, H, C, 64);

    const dim3 gg(1, (NN + 63) / 64);   // 782 blocks
    // projection: xbuf = n_feats @ Wp + bp            (fp32 out)
    mfma_gemm<0, 128><<<gg, 256, 0, stream>>>(n_feats, bt_ph, bt_pl, bp, nullptr,
                                              xbuf, nullptr, NN, H, F);
    // layer 1 GEMM: hbuf = bf16((xbuf @ W1) * rs_out)
    mfma_gemm<1, 128><<<gg, 256, 0, stream>>>(xbuf, bt_1h, bt_1l, nullptr, rs_out,
                                              nullptr, hbuf, NN, H, H);
    aggregate_bf16<<<(NN + 3) / 4, 256, 0, stream>>>((const unsigned int*)hbuf, csr_src,
                                                     row_start, cnt_in, rs_in, b1, xbuf, NN);
    // layer 2
    mfma_gemm<1, 128><<<gg, 256, 0, stream>>>(xbuf, bt_2h, bt_2l, nullptr, rs_out,
                                              nullptr, hbuf, NN, H, H);
    aggregate_bf16<<<(NN + 3) / 4, 256, 0, stream>>>((const unsigned int*)hbuf, csr_src,
                                                     row_start, cnt_in, rs_in, b2, xbuf, NN);
    // classifier: out = xbuf @ Wc + bc  (B padded to 64 cols, store-masked to 40)
    mfma_gemm<0, 64><<<gg, 256, 0, stream>>>(xbuf, bt_ch, bt_cl, bc, nullptr,
                                             out, nullptr, NN, C, H);
}

// Round 6
// 417.609 us; speedup vs baseline: 1.0026x; 1.0026x over previous
//
#include <hip/hip_runtime.h>

// Problem constants (from reference setup_inputs)
constexpr int NN = 50000;   // nodes
constexpr int H  = 128;     // hidden
constexpr int F  = 256;     // input features
constexpr int C  = 40;      // classes

// graph-prepass partitioning: 16384-node ranges (64 KB LDS), 4 ranges, 32 chunks
constexpr int RSZ = 16384;
constexpr int NRG = (NN + RSZ - 1) / RSZ;   // 4
constexpr int CH  = 32;

typedef short bf16x8 __attribute__((ext_vector_type(8)));
typedef short s16x4  __attribute__((ext_vector_type(4)));
typedef float f32x4  __attribute__((ext_vector_type(4)));

__device__ inline unsigned short f2bf(float f) {          // RNE fp32 -> bf16
    unsigned u = __float_as_uint(f);
    u += 0x7fff + ((u >> 16) & 1);
    return (unsigned short)(u >> 16);
}
__device__ inline float bf2f(unsigned short s) {
    return __uint_as_float(((unsigned)s) << 16);
}

// ------------------------------------------------ graph prepass (LDS histograms)
// Histogram of `keys` restricted to node range blockIdx.x, edge chunk blockIdx.y.
__global__ __launch_bounds__(256) void hist_node(
        const int* __restrict__ keys, int* __restrict__ partials, int E) {
    __shared__ int hist[RSZ];
    const int r = blockIdx.x;
    const int b = blockIdx.y;
    for (int i = threadIdx.x; i < RSZ; i += 256) hist[i] = 0;
    __syncthreads();
    const int base = r * RSZ;
    const int CE = (E + CH - 1) / CH;
    const int e0 = b * CE, e1 = min(E, e0 + CE);
    for (int e = e0 + threadIdx.x; e < e1; e += 256) {
        unsigned o = (unsigned)(keys[e] - base);
        if (o < (unsigned)RSZ) atomicAdd(&hist[o], 1);
    }
    __syncthreads();
    const long po = ((long)r * CH + b) * RSZ;
    for (int i = threadIdx.x; i < RSZ; i += 256) partials[po + i] = hist[i];
}

// Per-node merge: out-deg total -> rs_out; in-deg total -> cnt_in, rs_in;
// p_in converted in-place to exclusive prefix over chunks (per-chunk cursor bases).
__global__ __launch_bounds__(256) void merge_deg(
        const int* __restrict__ p_out, int* __restrict__ p_in,
        int* __restrict__ cnt_in, float* __restrict__ rs_out, float* __restrict__ rs_in,
        int n) {
    const int i = blockIdx.x * 256 + threadIdx.x;
    if (i >= n) return;
    const int r = i / RSZ, off = i % RSZ;
    const long pb = (long)r * CH * RSZ + off;
    int so = 0, si = 0;
#pragma unroll 4
    for (int b = 0; b < CH; b++) {
        so += p_out[pb + (long)b * RSZ];
        int v = p_in[pb + (long)b * RSZ];
        p_in[pb + (long)b * RSZ] = si;
        si += v;
    }
    cnt_in[i] = si;
    rs_out[i] = rsqrtf((float)max(so, 1));
    rs_in[i]  = rsqrtf((float)max(si, 1));
}

// CSR fill with LDS cursors — no global atomics.
__global__ __launch_bounds__(256) void fill_csr_part(
        const int* __restrict__ src, const int* __restrict__ dst,
        const int* __restrict__ row_start, const int* __restrict__ p_in,
        int* __restrict__ csr_src, int E, int n_nodes) {
    __shared__ int cur[RSZ];
    const int r = blockIdx.x;
    const int b = blockIdx.y;
    const int base = r * RSZ;
    const long po = ((long)r * CH + b) * RSZ;
    for (int i = threadIdx.x; i < RSZ; i += 256) {
        int node = base + i;
        cur[i] = (node < n_nodes ? row_start[node] : 0) + p_in[po + i];
    }
    __syncthreads();
    const int CE = (E + CH - 1) / CH;
    const int e0 = b * CE, e1 = min(E, e0 + CE);
    for (int e = e0 + threadIdx.x; e < e1; e += 256) {
        int d = dst[e];
        unsigned dof = (unsigned)(d - base);
        if (dof < (unsigned)RSZ) {
            int pos = atomicAdd(&cur[dof], 1);   // LDS atomic
            csr_src[pos] = src[e];
        }
    }
}

// ------------------------------------------------ parallel exclusive scan
__global__ __launch_bounds__(256) void scan_partial(
        const int* __restrict__ cnt, int* __restrict__ excl,
        int* __restrict__ block_sums, int n) {
    __shared__ int sh[256];
    const int t = threadIdx.x;
    const int i = blockIdx.x * 256 + t;
    const int v = (i < n) ? cnt[i] : 0;
    sh[t] = v;
    __syncthreads();
#pragma unroll
    for (int off = 1; off < 256; off <<= 1) {
        int u = (t >= off) ? sh[t - off] : 0;
        __syncthreads();
        sh[t] += u;
        __syncthreads();
    }
    if (i < n) excl[i] = sh[t] - v;
    if (t == 255) block_sums[blockIdx.x] = sh[255];
}

__global__ __launch_bounds__(256) void scan_sums(int* __restrict__ block_sums, int nb) {
    __shared__ int sh[256];
    const int t = threadIdx.x;
    const int v = (t < nb) ? block_sums[t] : 0;
    sh[t] = v;
    __syncthreads();
#pragma unroll
    for (int off = 1; off < 256; off <<= 1) {
        int u = (t >= off) ? sh[t - off] : 0;
        __syncthreads();
        sh[t] += u;
        __syncthreads();
    }
    if (t < nb) block_sums[t] = sh[t] - v;
}

__global__ __launch_bounds__(256) void scan_add(
        int* __restrict__ row_start, const int* __restrict__ block_sums, int n) {
    const int i = blockIdx.x * 256 + threadIdx.x;
    if (i < n) row_start[i] += block_sums[blockIdx.x];
}

// ------------------------------------------------ weight prep: transpose + hi/lo split
__global__ void prep_Bt(const float* __restrict__ W,
                        unsigned short* __restrict__ Bth, unsigned short* __restrict__ Btl,
                        int K, int N, int NP) {
    int i = blockIdx.x * blockDim.x + threadIdx.x;
    if (i >= NP * K) return;
    int n = i / K, k = i % K;
    float v = (n < N) ? W[(long)k * N + n] : 0.f;
    unsigned short hh = f2bf(v);
    unsigned short ll = f2bf(v - bf2f(hh));
    Bth[(long)n * K + k] = hh;
    Btl[(long)n * K + k] = ll;
}

// ------------------------------------------------ MFMA split-bf16 GEMM
// C = A(fp32,[M,K]) @ B(fp32,[K,Nout]) via hi/lo bf16 split (3 MFMA products).
// MODE 0: outf = acc + bias[gc]   (gc < Nout mask);  MODE 1: outh = bf16(acc*row_scale)
template<int MODE, int BN>
__global__ __launch_bounds__(256) void mfma_gemm(
        const float* __restrict__ A,
        const unsigned short* __restrict__ Bth, const unsigned short* __restrict__ Btl,
        const float* __restrict__ bias, const float* __restrict__ row_scale,
        float* __restrict__ outf, unsigned short* __restrict__ outh,
        int M, int Nout, int K) {
    constexpr int NT = BN / 64;
    __shared__ unsigned short As_h[4 * 65 * 8];
    __shared__ unsigned short As_l[4 * 65 * 8];
    __shared__ unsigned short Bs_h[4 * (BN + 1) * 8];
    __shared__ unsigned short Bs_l[4 * (BN + 1) * 8];

    const int tid  = threadIdx.x;
    const int wave = tid >> 6;
    const int lane = tid & 63;
    const int quad = lane >> 4;
    const int lr   = lane & 15;
    const int row0 = blockIdx.y * 64;
    const int wn0  = wave * (BN / 4);

    f32x4 acc[4][NT];
#pragma unroll
    for (int mt = 0; mt < 4; mt++)
#pragma unroll
        for (int nt = 0; nt < NT; nt++)
            acc[mt][nt] = (f32x4){0.f, 0.f, 0.f, 0.f};

    for (int k0 = 0; k0 < K; k0 += 32) {
#pragma unroll
        for (int r = 0; r < 2; r++) {
            int c   = tid + 256 * r;
            int row = c >> 3;
            int k4f = c & 7;
            int gr  = row0 + row;
            float4 v = make_float4(0.f, 0.f, 0.f, 0.f);
            if (gr < M) v = *(const float4*)&A[(long)gr * K + k0 + k4f * 4];
            unsigned short h0 = f2bf(v.x), h1 = f2bf(v.y), h2 = f2bf(v.z), h3 = f2bf(v.w);
            unsigned short l0 = f2bf(v.x - bf2f(h0));
            unsigned short l1 = f2bf(v.y - bf2f(h1));
            unsigned short l2 = f2bf(v.z - bf2f(h2));
            unsigned short l3 = f2bf(v.w - bf2f(h3));
            int base = (k4f >> 1) * 520 + row * 8 + (k4f & 1) * 4;
            s16x4 hv; hv[0] = (short)h0; hv[1] = (short)h1; hv[2] = (short)h2; hv[3] = (short)h3;
            s16x4 lv; lv[0] = (short)l0; lv[1] = (short)l1; lv[2] = (short)l2; lv[3] = (short)l3;
            *(s16x4*)&As_h[base] = hv;
            *(s16x4*)&As_l[base] = lv;
        }
        for (int c = tid; c < BN * 4; c += 256) {
            int n  = c >> 2;
            int k4 = c & 3;
            long off = (long)n * K + k0 + k4 * 8;
            uint4 vh = *(const uint4*)&Bth[off];
            uint4 vl = *(const uint4*)&Btl[off];
            int bbase = k4 * (BN + 1) * 8 + n * 8;
            *(uint4*)&Bs_h[bbase] = vh;
            *(uint4*)&Bs_l[bbase] = vl;
        }
        __syncthreads();

        bf16x8 ah[4], al[4], bh[NT], bl[NT];
#pragma unroll
        for (int mt = 0; mt < 4; mt++) {
            int ab = quad * 520 + (mt * 16 + lr) * 8;
            ah[mt] = *(const bf16x8*)&As_h[ab];
            al[mt] = *(const bf16x8*)&As_l[ab];
        }
#pragma unroll
        for (int nt = 0; nt < NT; nt++) {
            int bb = quad * (BN + 1) * 8 + (wn0 + nt * 16 + lr) * 8;
            bh[nt] = *(const bf16x8*)&Bs_h[bb];
            bl[nt] = *(const bf16x8*)&Bs_l[bb];
        }
#pragma unroll
        for (int mt = 0; mt < 4; mt++)
#pragma unroll
            for (int nt = 0; nt < NT; nt++) {
                acc[mt][nt] = __builtin_amdgcn_mfma_f32_16x16x32_bf16(ah[mt], bh[nt], acc[mt][nt], 0, 0, 0);
                acc[mt][nt] = __builtin_amdgcn_mfma_f32_16x16x32_bf16(al[mt], bh[nt], acc[mt][nt], 0, 0, 0);
                acc[mt][nt] = __builtin_amdgcn_mfma_f32_16x16x32_bf16(ah[mt], bl[nt], acc[mt][nt], 0, 0, 0);
            }
        __syncthreads();
    }

#pragma unroll
    for (int mt = 0; mt < 4; mt++) {
#pragma unroll
        for (int nt = 0; nt < NT; nt++) {
            int gc = wn0 + nt * 16 + lr;
#pragma unroll
            for (int r = 0; r < 4; r++) {
                int gr = row0 + mt * 16 + quad * 4 + r;
                if (gr >= M) continue;
                float v = acc[mt][nt][r];
                if (MODE == 0) {
                    if (gc < Nout) outf[(long)gr * Nout + gc] = v + bias[gc];
                } else {
                    v *= row_scale[gr];
                    outh[(long)gr * Nout + gc] = f2bf(v);
                }
            }
        }
    }
}

// ---------------------------------------------------------------- aggregation (bf16 h)
__global__ __launch_bounds__(256) void aggregate_bf16(
        const unsigned int* __restrict__ h, const int* __restrict__ csr_src,
        const int* __restrict__ row_start, const int* __restrict__ cnt_in,
        const float* __restrict__ rs_in, const float* __restrict__ bias,
        float* __restrict__ out, int nodes) {
    const int wave = threadIdx.x >> 6;
    const int lane = threadIdx.x & 63;
    const int v = blockIdx.x * 4 + wave;
    if (v >= nodes) return;
    const int s0  = row_start[v];
    const int cnt = cnt_in[v];
    float ax = 0.f, ay = 0.f;
    int i = 0;
    for (; i + 4 <= cnt; i += 4) {
        int sa = csr_src[s0 + i];
        int sb = csr_src[s0 + i + 1];
        int sc = csr_src[s0 + i + 2];
        int sd = csr_src[s0 + i + 3];
        unsigned ua = h[(long)sa * 64 + lane];
        unsigned ub = h[(long)sb * 64 + lane];
        unsigned uc = h[(long)sc * 64 + lane];
        unsigned ud = h[(long)sd * 64 + lane];
        ax += __uint_as_float(ua << 16) + __uint_as_float(ub << 16)
            + __uint_as_float(uc << 16) + __uint_as_float(ud << 16);
        ay += __uint_as_float(ua & 0xffff0000u) + __uint_as_float(ub & 0xffff0000u)
            + __uint_as_float(uc & 0xffff0000u) + __uint_as_float(ud & 0xffff0000u);
    }
    for (; i < cnt; i++) {
        int s = csr_src[s0 + i];
        unsigned u = h[(long)s * 64 + lane];
        ax += __uint_as_float(u << 16);
        ay += __uint_as_float(u & 0xffff0000u);
    }
    const float rs = rs_in[v];
    const float2 bb = ((const float2*)bias)[lane];
    float2 o;
    o.x = fmaxf(ax * rs + bb.x, 0.f);
    o.y = fmaxf(ay * rs + bb.y, 0.f);
    ((float2*)out)[(long)v * 64 + lane] = o;
}

// ---------------------------------------------------------------- launch
extern "C" void kernel_launch(void* const* d_in, const int* in_sizes, int n_in,
                              void* d_out, int out_size, void* d_ws, size_t ws_size,
                              hipStream_t stream) {
    const float* n_feats = (const float*)d_in[0];
    const int*   src     = (const int*)d_in[1];
    const int*   dst     = (const int*)d_in[2];
    const float* Wp      = (const float*)d_in[3];
    const float* bp      = (const float*)d_in[4];
    const float* W1      = (const float*)d_in[5];
    const float* b1      = (const float*)d_in[6];
    const float* W2      = (const float*)d_in[7];
    const float* b2      = (const float*)d_in[8];
    const float* Wc      = (const float*)d_in[9];
    const float* bc      = (const float*)d_in[10];
    float* out = (float*)d_out;
    const int E = in_sizes[1];

    const long PSZ = (long)NRG * CH * RSZ;     // partials: 2,097,152 ints (8 MB)

    // workspace layout
    char* ws = (char*)d_ws;
    float*          xbuf  = (float*)ws;                             // NN*128 fp32
    unsigned short* hbuf  = (unsigned short*)(xbuf + (long)NN * H); // NN*128 bf16
    unsigned short* bt_ph = hbuf + (long)NN * H;                    // 128*256
    unsigned short* bt_pl = bt_ph + 128 * 256;
    unsigned short* bt_1h = bt_pl + 128 * 256;                      // 128*128
    unsigned short* bt_1l = bt_1h + 128 * 128;
    unsigned short* bt_2h = bt_1l + 128 * 128;
    unsigned short* bt_2l = bt_2h + 128 * 128;
    unsigned short* bt_ch = bt_2l + 128 * 128;                      // 64*128
    unsigned short* bt_cl = bt_ch + 64 * 128;
    int*   cnt_in     = (int*)(bt_cl + 64 * 128);                   // N
    int*   row_start  = cnt_in + NN;                                // N
    float* rs_out     = (float*)(row_start + NN);                   // N
    float* rs_in      = rs_out + NN;                                // N
    int*   block_sums = (int*)(rs_in + NN);                         // 256
    int*   p_out      = block_sums + 256;                           // PSZ (aliases csr region)
    int*   csr_src    = p_out;                                      // E (<= PSZ; p_out dead before fill)
    int*   p_in       = p_out + PSZ;                                // PSZ

    const int TB = 256;
    const int NB = (NN + 255) / 256;
    const dim3 ghist(NRG, CH);      // (4, 32) = 128 blocks
    // graph prepass (no global atomics)
    hist_node<<<ghist, 256, 0, stream>>>(src, p_out, E);
    hist_node<<<ghist, 256, 0, stream>>>(dst, p_in, E);
    merge_deg<<<(NN + TB - 1) / TB, TB, 0, stream>>>(p_out, p_in, cnt_in, rs_out, rs_in, NN);
    scan_partial<<<NB, 256, 0, stream>>>(cnt_in, row_start, block_sums, NN);
    scan_sums<<<1, 256, 0, stream>>>(block_sums, NB);
    scan_add<<<NB, 256, 0, stream>>>(row_start, block_sums, NN);
    fill_csr_part<<<ghist, 256, 0, stream>>>(src, dst, row_start, p_in, csr_src, E, NN);
    // weight prep (transpose + hi/lo split)
    prep_Bt<<<(128 * F + TB - 1) / TB, TB, 0, stream>>>(Wp, bt_ph, bt_pl, F, H, 128);
    prep_Bt<<<(128 * H + TB - 1) / TB, TB, 0, stream>>>(W1, bt_1h, bt_1l, H, H, 128);
    prep_Bt<<<(128 * H + TB - 1) / TB, TB, 0, stream>>>(W2, bt_2h, bt_2l, H, H, 128);
    prep_Bt<<<(64 * H + TB - 1) / TB, TB, 0, stream>>>(Wc, bt_ch, bt_cl, H, C, 64);

    const dim3 gg(1, (NN + 63) / 64);   // 782 blocks
    // projection: xbuf = n_feats @ Wp + bp            (fp32 out)
    mfma_gemm<0, 128><<<gg, 256, 0, stream>>>(n_feats, bt_ph, bt_pl, bp, nullptr,
                                              xbuf, nullptr, NN, H, F);
    // layer 1 GEMM: hbuf = bf16((xbuf @ W1) * rs_out)
    mfma_gemm<1, 128><<<gg, 256, 0, stream>>>(xbuf, bt_1h, bt_1l, nullptr, rs_out,
                                              nullptr, hbuf, NN, H, H);
    aggregate_bf16<<<(NN + 3) / 4, 256, 0, stream>>>((const unsigned int*)hbuf, csr_src,
                                                     row_start, cnt_in, rs_in, b1, xbuf, NN);
    // layer 2
    mfma_gemm<1, 128><<<gg, 256, 0, stream>>>(xbuf, bt_2h, bt_2l, nullptr, rs_out,
                                              nullptr, hbuf, NN, H, H);
    aggregate_bf16<<<(NN + 3) / 4, 256, 0, stream>>>((const unsigned int*)hbuf, csr_src,
                                                     row_start, cnt_in, rs_in, b2, xbuf, NN);
    // classifier: out = xbuf @ Wc + bc  (B padded to 64 cols, store-masked to 40)
    mfma_gemm<0, 64><<<gg, 256, 0, stream>>>(xbuf, bt_ch, bt_cl, bc, nullptr,
                                             out, nullptr, NN, C, H);
}

// Round 7
// 369.464 us; speedup vs baseline: 1.1332x; 1.1303x over previous
//
#include <hip/hip_runtime.h>

// Problem constants (from reference setup_inputs)
constexpr int NN = 50000;   // nodes
constexpr int H  = 128;     // hidden
constexpr int F  = 256;     // input features
constexpr int C  = 40;      // classes

// graph-prepass partitioning: 8192-node ranges (32 KB LDS -> 5 blocks/CU),
// 7 ranges, 48 edge chunks -> grid 336 blocks (all CUs busy).
constexpr int RSZ = 8192;
constexpr int NRG = (NN + RSZ - 1) / RSZ;   // 7
constexpr int CH  = 48;

typedef short bf16x8 __attribute__((ext_vector_type(8)));
typedef short s16x4  __attribute__((ext_vector_type(4)));
typedef float f32x4  __attribute__((ext_vector_type(4)));

__device__ inline unsigned short f2bf(float f) {          // RNE fp32 -> bf16
    unsigned u = __float_as_uint(f);
    u += 0x7fff + ((u >> 16) & 1);
    return (unsigned short)(u >> 16);
}
__device__ inline float bf2f(unsigned short s) {
    return __uint_as_float(((unsigned)s) << 16);
}

// ------------------------------------------------ graph prepass (LDS histograms)
// Histogram of `keys` restricted to node range blockIdx.x, edge chunk blockIdx.y.
__global__ __launch_bounds__(256) void hist_node(
        const int* __restrict__ keys, int* __restrict__ partials, int E) {
    __shared__ int hist[RSZ];
    const int r = blockIdx.x;
    const int b = blockIdx.y;
    for (int i = threadIdx.x; i < RSZ; i += 256) hist[i] = 0;
    __syncthreads();
    const int base = r * RSZ;
    const int CE = (E + CH - 1) / CH;
    const int e0 = b * CE, e1 = min(E, e0 + CE);
#pragma unroll 4
    for (int e = e0 + threadIdx.x; e < e1; e += 256) {
        unsigned o = (unsigned)(keys[e] - base);
        if (o < (unsigned)RSZ) atomicAdd(&hist[o], 1);
    }
    __syncthreads();
    const long po = ((long)r * CH + b) * RSZ;
    for (int i = threadIdx.x; i < RSZ; i += 256) partials[po + i] = hist[i];
}

// Per-node merge: out-deg total -> rs_out; in-deg total -> cnt_in, rs_in;
// p_in converted in-place to exclusive prefix over chunks (per-chunk cursor bases).
__global__ __launch_bounds__(256) void merge_deg(
        const int* __restrict__ p_out, int* __restrict__ p_in,
        int* __restrict__ cnt_in, float* __restrict__ rs_out, float* __restrict__ rs_in,
        int n) {
    const int i = blockIdx.x * 256 + threadIdx.x;
    if (i >= n) return;
    const int r = i / RSZ, off = i % RSZ;
    const long pb = (long)r * CH * RSZ + off;
    int so = 0, si = 0;
#pragma unroll 4
    for (int b = 0; b < CH; b++) {
        so += p_out[pb + (long)b * RSZ];
        int v = p_in[pb + (long)b * RSZ];
        p_in[pb + (long)b * RSZ] = si;
        si += v;
    }
    cnt_in[i] = si;
    rs_out[i] = rsqrtf((float)max(so, 1));
    rs_in[i]  = rsqrtf((float)max(si, 1));
}

// CSR fill with LDS cursors — no global atomics.
__global__ __launch_bounds__(256) void fill_csr_part(
        const int* __restrict__ src, const int* __restrict__ dst,
        const int* __restrict__ row_start, const int* __restrict__ p_in,
        int* __restrict__ csr_src, int E, int n_nodes) {
    __shared__ int cur[RSZ];
    const int r = blockIdx.x;
    const int b = blockIdx.y;
    const int base = r * RSZ;
    const long po = ((long)r * CH + b) * RSZ;
    for (int i = threadIdx.x; i < RSZ; i += 256) {
        int node = base + i;
        cur[i] = (node < n_nodes ? row_start[node] : 0) + p_in[po + i];
    }
    __syncthreads();
    const int CE = (E + CH - 1) / CH;
    const int e0 = b * CE, e1 = min(E, e0 + CE);
#pragma unroll 4
    for (int e = e0 + threadIdx.x; e < e1; e += 256) {
        int d = dst[e];
        unsigned dof = (unsigned)(d - base);
        if (dof < (unsigned)RSZ) {
            int pos = atomicAdd(&cur[dof], 1);   // LDS atomic
            csr_src[pos] = src[e];
        }
    }
}

// ------------------------------------------------ parallel exclusive scan
__global__ __launch_bounds__(256) void scan_partial(
        const int* __restrict__ cnt, int* __restrict__ excl,
        int* __restrict__ block_sums, int n) {
    __shared__ int sh[256];
    const int t = threadIdx.x;
    const int i = blockIdx.x * 256 + t;
    const int v = (i < n) ? cnt[i] : 0;
    sh[t] = v;
    __syncthreads();
#pragma unroll
    for (int off = 1; off < 256; off <<= 1) {
        int u = (t >= off) ? sh[t - off] : 0;
        __syncthreads();
        sh[t] += u;
        __syncthreads();
    }
    if (i < n) excl[i] = sh[t] - v;
    if (t == 255) block_sums[blockIdx.x] = sh[255];
}

__global__ __launch_bounds__(256) void scan_sums(int* __restrict__ block_sums, int nb) {
    __shared__ int sh[256];
    const int t = threadIdx.x;
    const int v = (t < nb) ? block_sums[t] : 0;
    sh[t] = v;
    __syncthreads();
#pragma unroll
    for (int off = 1; off < 256; off <<= 1) {
        int u = (t >= off) ? sh[t - off] : 0;
        __syncthreads();
        sh[t] += u;
        __syncthreads();
    }
    if (t < nb) block_sums[t] = sh[t] - v;
}

__global__ __launch_bounds__(256) void scan_add(
        int* __restrict__ row_start, const int* __restrict__ block_sums, int n) {
    const int i = blockIdx.x * 256 + threadIdx.x;
    if (i < n) row_start[i] += block_sums[blockIdx.x];
}

// ------------------------------------------------ weight prep: transpose + hi/lo split
__global__ void prep_Bt(const float* __restrict__ W,
                        unsigned short* __restrict__ Bth, unsigned short* __restrict__ Btl,
                        int K, int N, int NP) {
    int i = blockIdx.x * blockDim.x + threadIdx.x;
    if (i >= NP * K) return;
    int n = i / K, k = i % K;
    float v = (n < N) ? W[(long)k * N + n] : 0.f;
    unsigned short hh = f2bf(v);
    unsigned short ll = f2bf(v - bf2f(hh));
    Bth[(long)n * K + k] = hh;
    Btl[(long)n * K + k] = ll;
}

// ------------------------------------------------ MFMA split-bf16 GEMM
// C = A(fp32,[M,K]) @ B(fp32,[K,Nout]) via hi/lo bf16 split (3 MFMA products).
// MODE 0: outf = acc + bias[gc]   (gc < Nout mask);  MODE 1: outh = bf16(acc*row_scale)
template<int MODE, int BN>
__global__ __launch_bounds__(256) void mfma_gemm(
        const float* __restrict__ A,
        const unsigned short* __restrict__ Bth, const unsigned short* __restrict__ Btl,
        const float* __restrict__ bias, const float* __restrict__ row_scale,
        float* __restrict__ outf, unsigned short* __restrict__ outh,
        int M, int Nout, int K) {
    constexpr int NT = BN / 64;
    __shared__ unsigned short As_h[4 * 65 * 8];
    __shared__ unsigned short As_l[4 * 65 * 8];
    __shared__ unsigned short Bs_h[4 * (BN + 1) * 8];
    __shared__ unsigned short Bs_l[4 * (BN + 1) * 8];

    const int tid  = threadIdx.x;
    const int wave = tid >> 6;
    const int lane = tid & 63;
    const int quad = lane >> 4;
    const int lr   = lane & 15;
    const int row0 = blockIdx.y * 64;
    const int wn0  = wave * (BN / 4);

    f32x4 acc[4][NT];
#pragma unroll
    for (int mt = 0; mt < 4; mt++)
#pragma unroll
        for (int nt = 0; nt < NT; nt++)
            acc[mt][nt] = (f32x4){0.f, 0.f, 0.f, 0.f};

    for (int k0 = 0; k0 < K; k0 += 32) {
#pragma unroll
        for (int r = 0; r < 2; r++) {
            int c   = tid + 256 * r;
            int row = c >> 3;
            int k4f = c & 7;
            int gr  = row0 + row;
            float4 v = make_float4(0.f, 0.f, 0.f, 0.f);
            if (gr < M) v = *(const float4*)&A[(long)gr * K + k0 + k4f * 4];
            unsigned short h0 = f2bf(v.x), h1 = f2bf(v.y), h2 = f2bf(v.z), h3 = f2bf(v.w);
            unsigned short l0 = f2bf(v.x - bf2f(h0));
            unsigned short l1 = f2bf(v.y - bf2f(h1));
            unsigned short l2 = f2bf(v.z - bf2f(h2));
            unsigned short l3 = f2bf(v.w - bf2f(h3));
            int base = (k4f >> 1) * 520 + row * 8 + (k4f & 1) * 4;
            s16x4 hv; hv[0] = (short)h0; hv[1] = (short)h1; hv[2] = (short)h2; hv[3] = (short)h3;
            s16x4 lv; lv[0] = (short)l0; lv[1] = (short)l1; lv[2] = (short)l2; lv[3] = (short)l3;
            *(s16x4*)&As_h[base] = hv;
            *(s16x4*)&As_l[base] = lv;
        }
        for (int c = tid; c < BN * 4; c += 256) {
            int n  = c >> 2;
            int k4 = c & 3;
            long off = (long)n * K + k0 + k4 * 8;
            uint4 vh = *(const uint4*)&Bth[off];
            uint4 vl = *(const uint4*)&Btl[off];
            int bbase = k4 * (BN + 1) * 8 + n * 8;
            *(uint4*)&Bs_h[bbase] = vh;
            *(uint4*)&Bs_l[bbase] = vl;
        }
        __syncthreads();

        bf16x8 ah[4], al[4], bh[NT], bl[NT];
#pragma unroll
        for (int mt = 0; mt < 4; mt++) {
            int ab = quad * 520 + (mt * 16 + lr) * 8;
            ah[mt] = *(const bf16x8*)&As_h[ab];
            al[mt] = *(const bf16x8*)&As_l[ab];
        }
#pragma unroll
        for (int nt = 0; nt < NT; nt++) {
            int bb = quad * (BN + 1) * 8 + (wn0 + nt * 16 + lr) * 8;
            bh[nt] = *(const bf16x8*)&Bs_h[bb];
            bl[nt] = *(const bf16x8*)&Bs_l[bb];
        }
#pragma unroll
        for (int mt = 0; mt < 4; mt++)
#pragma unroll
            for (int nt = 0; nt < NT; nt++) {
                acc[mt][nt] = __builtin_amdgcn_mfma_f32_16x16x32_bf16(ah[mt], bh[nt], acc[mt][nt], 0, 0, 0);
                acc[mt][nt] = __builtin_amdgcn_mfma_f32_16x16x32_bf16(al[mt], bh[nt], acc[mt][nt], 0, 0, 0);
                acc[mt][nt] = __builtin_amdgcn_mfma_f32_16x16x32_bf16(ah[mt], bl[nt], acc[mt][nt], 0, 0, 0);
            }
        __syncthreads();
    }

#pragma unroll
    for (int mt = 0; mt < 4; mt++) {
#pragma unroll
        for (int nt = 0; nt < NT; nt++) {
            int gc = wn0 + nt * 16 + lr;
#pragma unroll
            for (int r = 0; r < 4; r++) {
                int gr = row0 + mt * 16 + quad * 4 + r;
                if (gr >= M) continue;
                float v = acc[mt][nt][r];
                if (MODE == 0) {
                    if (gc < Nout) outf[(long)gr * Nout + gc] = v + bias[gc];
                } else {
                    v *= row_scale[gr];
                    outh[(long)gr * Nout + gc] = f2bf(v);
                }
            }
        }
    }
}

// ---------------------------------------------------------------- aggregation (bf16 h)
__global__ __launch_bounds__(256) void aggregate_bf16(
        const unsigned int* __restrict__ h, const int* __restrict__ csr_src,
        const int* __restrict__ row_start, const int* __restrict__ cnt_in,
        const float* __restrict__ rs_in, const float* __restrict__ bias,
        float* __restrict__ out, int nodes) {
    const int wave = threadIdx.x >> 6;
    const int lane = threadIdx.x & 63;
    const int v = blockIdx.x * 4 + wave;
    if (v >= nodes) return;
    const int s0  = row_start[v];
    const int cnt = cnt_in[v];
    float ax = 0.f, ay = 0.f;
    int i = 0;
    for (; i + 4 <= cnt; i += 4) {
        int sa = csr_src[s0 + i];
        int sb = csr_src[s0 + i + 1];
        int sc = csr_src[s0 + i + 2];
        int sd = csr_src[s0 + i + 3];
        unsigned ua = h[(long)sa * 64 + lane];
        unsigned ub = h[(long)sb * 64 + lane];
        unsigned uc = h[(long)sc * 64 + lane];
        unsigned ud = h[(long)sd * 64 + lane];
        ax += __uint_as_float(ua << 16) + __uint_as_float(ub << 16)
            + __uint_as_float(uc << 16) + __uint_as_float(ud << 16);
        ay += __uint_as_float(ua & 0xffff0000u) + __uint_as_float(ub & 0xffff0000u)
            + __uint_as_float(uc & 0xffff0000u) + __uint_as_float(ud & 0xffff0000u);
    }
    for (; i < cnt; i++) {
        int s = csr_src[s0 + i];
        unsigned u = h[(long)s * 64 + lane];
        ax += __uint_as_float(u << 16);
        ay += __uint_as_float(u & 0xffff0000u);
    }
    const float rs = rs_in[v];
    const float2 bb = ((const float2*)bias)[lane];
    float2 o;
    o.x = fmaxf(ax * rs + bb.x, 0.f);
    o.y = fmaxf(ay * rs + bb.y, 0.f);
    ((float2*)out)[(long)v * 64 + lane] = o;
}

// ---------------------------------------------------------------- launch
extern "C" void kernel_launch(void* const* d_in, const int* in_sizes, int n_in,
                              void* d_out, int out_size, void* d_ws, size_t ws_size,
                              hipStream_t stream) {
    const float* n_feats = (const float*)d_in[0];
    const int*   src     = (const int*)d_in[1];
    const int*   dst     = (const int*)d_in[2];
    const float* Wp      = (const float*)d_in[3];
    const float* bp      = (const float*)d_in[4];
    const float* W1      = (const float*)d_in[5];
    const float* b1      = (const float*)d_in[6];
    const float* W2      = (const float*)d_in[7];
    const float* b2      = (const float*)d_in[8];
    const float* Wc      = (const float*)d_in[9];
    const float* bc      = (const float*)d_in[10];
    float* out = (float*)d_out;
    const int E = in_sizes[1];

    const long PSZ = (long)NRG * CH * RSZ;     // partials: 2,752,512 ints (11.0 MB)

    // workspace layout (aliasing: p_in <-> hbuf, p_out <-> csr_src)
    char* ws = (char*)d_ws;
    float*          xbuf  = (float*)ws;                             // NN*128 fp32
    unsigned short* hbuf  = (unsigned short*)(xbuf + (long)NN * H); // NN*128 bf16 (12.8 MB)
    int*            p_in  = (int*)hbuf;                             // PSZ (11.0 MB, dead before hbuf written)
    unsigned short* bt_ph = hbuf + (long)NN * H;                    // 128*256
    unsigned short* bt_pl = bt_ph + 128 * 256;
    unsigned short* bt_1h = bt_pl + 128 * 256;                      // 128*128
    unsigned short* bt_1l = bt_1h + 128 * 128;
    unsigned short* bt_2h = bt_1l + 128 * 128;
    unsigned short* bt_2l = bt_2h + 128 * 128;
    unsigned short* bt_ch = bt_2l + 128 * 128;                      // 64*128
    unsigned short* bt_cl = bt_ch + 64 * 128;
    int*   cnt_in     = (int*)(bt_cl + 64 * 128);                   // N
    int*   row_start  = cnt_in + NN;                                // N
    float* rs_out     = (float*)(row_start + NN);                   // N
    float* rs_in      = rs_out + NN;                                // N
    int*   block_sums = (int*)(rs_in + NN);                         // 256
    int*   p_out      = block_sums + 256;                           // PSZ
    int*   csr_src    = p_out;                                      // E (p_out dead before fill)

    const int TB = 256;
    const int NB = (NN + 255) / 256;
    const dim3 ghist(NRG, CH);      // (7, 48) = 336 blocks
    // graph prepass (no global atomics)
    hist_node<<<ghist, 256, 0, stream>>>(src, p_out, E);
    hist_node<<<ghist, 256, 0, stream>>>(dst, p_in, E);
    merge_deg<<<(NN + TB - 1) / TB, TB, 0, stream>>>(p_out, p_in, cnt_in, rs_out, rs_in, NN);
    scan_partial<<<NB, 256, 0, stream>>>(cnt_in, row_start, block_sums, NN);
    scan_sums<<<1, 256, 0, stream>>>(block_sums, NB);
    scan_add<<<NB, 256, 0, stream>>>(row_start, block_sums, NN);
    fill_csr_part<<<ghist, 256, 0, stream>>>(src, dst, row_start, p_in, csr_src, E, NN);
    // weight prep (transpose + hi/lo split)
    prep_Bt<<<(128 * F + TB - 1) / TB, TB, 0, stream>>>(Wp, bt_ph, bt_pl, F, H, 128);
    prep_Bt<<<(128 * H + TB - 1) / TB, TB, 0, stream>>>(W1, bt_1h, bt_1l, H, H, 128);
    prep_Bt<<<(128 * H + TB - 1) / TB, TB, 0, stream>>>(W2, bt_2h, bt_2l, H, H, 128);
    prep_Bt<<<(64 * H + TB - 1) / TB, TB, 0, stream>>>(Wc, bt_ch, bt_cl, H, C, 64);

    const dim3 gg(1, (NN + 63) / 64);   // 782 blocks
    // projection: xbuf = n_feats @ Wp + bp            (fp32 out)
    mfma_gemm<0, 128><<<gg, 256, 0, stream>>>(n_feats, bt_ph, bt_pl, bp, nullptr,
                                              xbuf, nullptr, NN, H, F);
    // layer 1 GEMM: hbuf = bf16((xbuf @ W1) * rs_out)   (p_in dead from here)
    mfma_gemm<1, 128><<<gg, 256, 0, stream>>>(xbuf, bt_1h, bt_1l, nullptr, rs_out,
                                              nullptr, hbuf, NN, H, H);
    aggregate_bf16<<<(NN + 3) / 4, 256, 0, stream>>>((const unsigned int*)hbuf, csr_src,
                                                     row_start, cnt_in, rs_in, b1, xbuf, NN);
    // layer 2
    mfma_gemm<1, 128><<<gg, 256, 0, stream>>>(xbuf, bt_2h, bt_2l, nullptr, rs_out,
                                              nullptr, hbuf, NN, H, H);
    aggregate_bf16<<<(NN + 3) / 4, 256, 0, stream>>>((const unsigned int*)hbuf, csr_src,
                                                     row_start, cnt_in, rs_in, b2, xbuf, NN);
    // classifier: out = xbuf @ Wc + bc  (B padded to 64 cols, store-masked to 40)
    mfma_gemm<0, 64><<<gg, 256, 0, stream>>>(xbuf, bt_ch, bt_cl, bc, nullptr,
                                             out, nullptr, NN, C, H);
}

// Round 8
// 344.631 us; speedup vs baseline: 1.2149x; 1.0721x over previous
//
#include <hip/hip_runtime.h>

// Problem constants (from reference setup_inputs)
constexpr int NN = 50000;   // nodes
constexpr int H  = 128;     // hidden
constexpr int F  = 256;     // input features
constexpr int C  = 40;      // classes

// graph-prepass partitioning: 8 ranges of 6400 nodes (25.6 KB LDS), 96 chunks
// -> grid (8,96)=768 blocks; linear id = r + 8*c => range r pinned to XCD r
// (round-robin heuristic), making csr scatter L2-local per XCD.
constexpr int RSZ = 6400;
constexpr int NRG = 8;
constexpr int CH  = 96;

typedef short bf16x8 __attribute__((ext_vector_type(8)));
typedef short s16x4  __attribute__((ext_vector_type(4)));
typedef float f32x4  __attribute__((ext_vector_type(4)));

__device__ inline unsigned short f2bf(float f) {          // RNE fp32 -> bf16
    unsigned u = __float_as_uint(f);
    u += 0x7fff + ((u >> 16) & 1);
    return (unsigned short)(u >> 16);
}
__device__ inline float bf2f(unsigned short s) {
    return __uint_as_float(((unsigned)s) << 16);
}

// ------------------------------------------------ graph prepass (LDS histograms)
__global__ __launch_bounds__(256) void hist_node(
        const int* __restrict__ keys, int* __restrict__ partials, int E) {
    __shared__ int hist[RSZ];
    const int r = blockIdx.x;
    const int b = blockIdx.y;
    for (int i = threadIdx.x; i < RSZ; i += 256) hist[i] = 0;
    __syncthreads();
    const int base = r * RSZ;
    const int CE = (E + CH - 1) / CH;
    const int e0 = b * CE, e1 = min(E, e0 + CE);
#pragma unroll 8
    for (int e = e0 + threadIdx.x; e < e1; e += 256) {
        unsigned o = (unsigned)(keys[e] - base);
        if (o < (unsigned)RSZ) atomicAdd(&hist[o], 1);
    }
    __syncthreads();
    const long po = ((long)r * CH + b) * RSZ;
    for (int i = threadIdx.x; i < RSZ; i += 256) partials[po + i] = hist[i];
}

// Per-node merge: out-deg -> rs_out; in-deg -> cnt_in, rs_in;
// p_in converted in-place to exclusive prefix over chunks (per-chunk cursor bases).
__global__ __launch_bounds__(256) void merge_deg(
        const int* __restrict__ p_out, int* __restrict__ p_in,
        int* __restrict__ cnt_in, float* __restrict__ rs_out, float* __restrict__ rs_in,
        int n) {
    const int i = blockIdx.x * 256 + threadIdx.x;
    if (i >= n) return;
    const int r = i / RSZ, off = i % RSZ;
    const long pb = (long)r * CH * RSZ + off;
    int so = 0, si = 0;
#pragma unroll 4
    for (int b = 0; b < CH; b++) {
        so += p_out[pb + (long)b * RSZ];
        int v = p_in[pb + (long)b * RSZ];
        p_in[pb + (long)b * RSZ] = si;
        si += v;
    }
    cnt_in[i] = si;
    rs_out[i] = rsqrtf((float)max(so, 1));
    rs_in[i]  = rsqrtf((float)max(si, 1));
}

// CSR fill with LDS cursors — no global atomics.
__global__ __launch_bounds__(256) void fill_csr_part(
        const int* __restrict__ src, const int* __restrict__ dst,
        const int* __restrict__ row_start, const int* __restrict__ p_in,
        int* __restrict__ csr_src, int E, int n_nodes) {
    __shared__ int cur[RSZ];
    const int r = blockIdx.x;
    const int b = blockIdx.y;
    const int base = r * RSZ;
    const long po = ((long)r * CH + b) * RSZ;
    for (int i = threadIdx.x; i < RSZ; i += 256) {
        int node = base + i;
        cur[i] = (node < n_nodes ? row_start[node] : 0) + p_in[po + i];
    }
    __syncthreads();
    const int CE = (E + CH - 1) / CH;
    const int e0 = b * CE, e1 = min(E, e0 + CE);
#pragma unroll 8
    for (int e = e0 + threadIdx.x; e < e1; e += 256) {
        int d = dst[e];
        unsigned dof = (unsigned)(d - base);
        if (dof < (unsigned)RSZ) {
            int pos = atomicAdd(&cur[dof], 1);   // LDS atomic
            csr_src[pos] = src[e];
        }
    }
}

// ------------------------------------------------ parallel exclusive scan
__global__ __launch_bounds__(256) void scan_partial(
        const int* __restrict__ cnt, int* __restrict__ excl,
        int* __restrict__ block_sums, int n) {
    __shared__ int sh[256];
    const int t = threadIdx.x;
    const int i = blockIdx.x * 256 + t;
    const int v = (i < n) ? cnt[i] : 0;
    sh[t] = v;
    __syncthreads();
#pragma unroll
    for (int off = 1; off < 256; off <<= 1) {
        int u = (t >= off) ? sh[t - off] : 0;
        __syncthreads();
        sh[t] += u;
        __syncthreads();
    }
    if (i < n) excl[i] = sh[t] - v;
    if (t == 255) block_sums[blockIdx.x] = sh[255];
}

__global__ __launch_bounds__(256) void scan_sums(int* __restrict__ block_sums, int nb) {
    __shared__ int sh[256];
    const int t = threadIdx.x;
    const int v = (t < nb) ? block_sums[t] : 0;
    sh[t] = v;
    __syncthreads();
#pragma unroll
    for (int off = 1; off < 256; off <<= 1) {
        int u = (t >= off) ? sh[t - off] : 0;
        __syncthreads();
        sh[t] += u;
        __syncthreads();
    }
    if (t < nb) block_sums[t] = sh[t] - v;
}

__global__ __launch_bounds__(256) void scan_add(
        int* __restrict__ row_start, const int* __restrict__ block_sums, int n) {
    const int i = blockIdx.x * 256 + threadIdx.x;
    if (i < n) row_start[i] += block_sums[blockIdx.x];
}

// ------------------------------------------------ weight prep: transpose + hi/lo split
__global__ void prep_Bt(const float* __restrict__ W,
                        unsigned short* __restrict__ Bth, unsigned short* __restrict__ Btl,
                        int K, int N, int NP) {
    int i = blockIdx.x * blockDim.x + threadIdx.x;
    if (i >= NP * K) return;
    int n = i / K, k = i % K;
    float v = (n < N) ? W[(long)k * N + n] : 0.f;
    unsigned short hh = f2bf(v);
    unsigned short ll = f2bf(v - bf2f(hh));
    Bth[(long)n * K + k] = hh;
    Btl[(long)n * K + k] = ll;
}

// ------------------------------------------------ MFMA split-bf16 GEMM
// C = A(fp32,[M,K]) @ B(fp32,[K,Nout]) via hi/lo bf16 split (3 MFMA products).
// MODE 0: outf = acc + bias[gc]   (gc < Nout mask);  MODE 1: outh = bf16(acc*row_scale)
template<int MODE, int BN>
__global__ __launch_bounds__(256) void mfma_gemm(
        const float* __restrict__ A,
        const unsigned short* __restrict__ Bth, const unsigned short* __restrict__ Btl,
        const float* __restrict__ bias, const float* __restrict__ row_scale,
        float* __restrict__ outf, unsigned short* __restrict__ outh,
        int M, int Nout, int K) {
    constexpr int NT = BN / 64;
    __shared__ unsigned short As_h[4 * 65 * 8];
    __shared__ unsigned short As_l[4 * 65 * 8];
    __shared__ unsigned short Bs_h[4 * (BN + 1) * 8];
    __shared__ unsigned short Bs_l[4 * (BN + 1) * 8];

    const int tid  = threadIdx.x;
    const int wave = tid >> 6;
    const int lane = tid & 63;
    const int quad = lane >> 4;
    const int lr   = lane & 15;
    const int row0 = blockIdx.y * 64;
    const int wn0  = wave * (BN / 4);

    f32x4 acc[4][NT];
#pragma unroll
    for (int mt = 0; mt < 4; mt++)
#pragma unroll
        for (int nt = 0; nt < NT; nt++)
            acc[mt][nt] = (f32x4){0.f, 0.f, 0.f, 0.f};

    for (int k0 = 0; k0 < K; k0 += 32) {
#pragma unroll
        for (int r = 0; r < 2; r++) {
            int c   = tid + 256 * r;
            int row = c >> 3;
            int k4f = c & 7;
            int gr  = row0 + row;
            float4 v = make_float4(0.f, 0.f, 0.f, 0.f);
            if (gr < M) v = *(const float4*)&A[(long)gr * K + k0 + k4f * 4];
            unsigned short h0 = f2bf(v.x), h1 = f2bf(v.y), h2 = f2bf(v.z), h3 = f2bf(v.w);
            unsigned short l0 = f2bf(v.x - bf2f(h0));
            unsigned short l1 = f2bf(v.y - bf2f(h1));
            unsigned short l2 = f2bf(v.z - bf2f(h2));
            unsigned short l3 = f2bf(v.w - bf2f(h3));
            int base = (k4f >> 1) * 520 + row * 8 + (k4f & 1) * 4;
            s16x4 hv; hv[0] = (short)h0; hv[1] = (short)h1; hv[2] = (short)h2; hv[3] = (short)h3;
            s16x4 lv; lv[0] = (short)l0; lv[1] = (short)l1; lv[2] = (short)l2; lv[3] = (short)l3;
            *(s16x4*)&As_h[base] = hv;
            *(s16x4*)&As_l[base] = lv;
        }
        for (int c = tid; c < BN * 4; c += 256) {
            int n  = c >> 2;
            int k4 = c & 3;
            long off = (long)n * K + k0 + k4 * 8;
            uint4 vh = *(const uint4*)&Bth[off];
            uint4 vl = *(const uint4*)&Btl[off];
            int bbase = k4 * (BN + 1) * 8 + n * 8;
            *(uint4*)&Bs_h[bbase] = vh;
            *(uint4*)&Bs_l[bbase] = vl;
        }
        __syncthreads();

        bf16x8 ah[4], al[4], bh[NT], bl[NT];
#pragma unroll
        for (int mt = 0; mt < 4; mt++) {
            int ab = quad * 520 + (mt * 16 + lr) * 8;
            ah[mt] = *(const bf16x8*)&As_h[ab];
            al[mt] = *(const bf16x8*)&As_l[ab];
        }
#pragma unroll
        for (int nt = 0; nt < NT; nt++) {
            int bb = quad * (BN + 1) * 8 + (wn0 + nt * 16 + lr) * 8;
            bh[nt] = *(const bf16x8*)&Bs_h[bb];
            bl[nt] = *(const bf16x8*)&Bs_l[bb];
        }
#pragma unroll
        for (int mt = 0; mt < 4; mt++)
#pragma unroll
            for (int nt = 0; nt < NT; nt++) {
                acc[mt][nt] = __builtin_amdgcn_mfma_f32_16x16x32_bf16(ah[mt], bh[nt], acc[mt][nt], 0, 0, 0);
                acc[mt][nt] = __builtin_amdgcn_mfma_f32_16x16x32_bf16(al[mt], bh[nt], acc[mt][nt], 0, 0, 0);
                acc[mt][nt] = __builtin_amdgcn_mfma_f32_16x16x32_bf16(ah[mt], bl[nt], acc[mt][nt], 0, 0, 0);
            }
        __syncthreads();
    }

#pragma unroll
    for (int mt = 0; mt < 4; mt++) {
#pragma unroll
        for (int nt = 0; nt < NT; nt++) {
            int gc = wn0 + nt * 16 + lr;
#pragma unroll
            for (int r = 0; r < 4; r++) {
                int gr = row0 + mt * 16 + quad * 4 + r;
                if (gr >= M) continue;
                float v = acc[mt][nt][r];
                if (MODE == 0) {
                    if (gc < Nout) outf[(long)gr * Nout + gc] = v + bias[gc];
                } else {
                    v *= row_scale[gr];
                    outh[(long)gr * Nout + gc] = f2bf(v);
                }
            }
        }
    }
}

// ---------------------------------------------------------------- aggregation (bf16 h)
__global__ __launch_bounds__(256) void aggregate_bf16(
        const unsigned int* __restrict__ h, const int* __restrict__ csr_src,
        const int* __restrict__ row_start, const int* __restrict__ cnt_in,
        const float* __restrict__ rs_in, const float* __restrict__ bias,
        float* __restrict__ out, int nodes) {
    const int wave = threadIdx.x >> 6;
    const int lane = threadIdx.x & 63;
    const int v = blockIdx.x * 4 + wave;
    if (v >= nodes) return;
    const int s0  = row_start[v];
    const int cnt = cnt_in[v];
    float ax = 0.f, ay = 0.f;
    int i = 0;
    for (; i + 8 <= cnt; i += 8) {
        int sidx[8];
#pragma unroll
        for (int j = 0; j < 8; j++) sidx[j] = csr_src[s0 + i + j];
        unsigned u[8];
#pragma unroll
        for (int j = 0; j < 8; j++) u[j] = h[(long)sidx[j] * 64 + lane];
#pragma unroll
        for (int j = 0; j < 8; j++) {
            ax += __uint_as_float(u[j] << 16);
            ay += __uint_as_float(u[j] & 0xffff0000u);
        }
    }
    for (; i < cnt; i++) {
        int s = csr_src[s0 + i];
        unsigned u = h[(long)s * 64 + lane];
        ax += __uint_as_float(u << 16);
        ay += __uint_as_float(u & 0xffff0000u);
    }
    const float rs = rs_in[v];
    const float2 bb = ((const float2*)bias)[lane];
    float2 o;
    o.x = fmaxf(ax * rs + bb.x, 0.f);
    o.y = fmaxf(ay * rs + bb.y, 0.f);
    ((float2*)out)[(long)v * 64 + lane] = o;
}

// ---------------------------------------------------------------- launch
extern "C" void kernel_launch(void* const* d_in, const int* in_sizes, int n_in,
                              void* d_out, int out_size, void* d_ws, size_t ws_size,
                              hipStream_t stream) {
    const float* n_feats = (const float*)d_in[0];
    const int*   src     = (const int*)d_in[1];
    const int*   dst     = (const int*)d_in[2];
    const float* Wp      = (const float*)d_in[3];
    const float* bp      = (const float*)d_in[4];
    const float* W1      = (const float*)d_in[5];
    const float* b1      = (const float*)d_in[6];
    const float* W2      = (const float*)d_in[7];
    const float* b2      = (const float*)d_in[8];
    const float* Wc      = (const float*)d_in[9];
    const float* bc      = (const float*)d_in[10];
    float* out = (float*)d_out;
    const int E = in_sizes[1];

    const long PSZ = (long)NRG * CH * RSZ;     // partials: 4,915,200 ints (19.66 MB)

    // workspace layout (aliasing: p_in <-> xbuf, p_out <-> csr_src)
    char* ws = (char*)d_ws;
    float*          xbuf  = (float*)ws;                             // NN*128 fp32 (25.6 MB)
    int*            p_in  = (int*)xbuf;                             // PSZ (19.66 MB, dead before xbuf written)
    unsigned short* hbuf  = (unsigned short*)(xbuf + (long)NN * H); // NN*128 bf16 (12.8 MB)
    unsigned short* bt_ph = hbuf + (long)NN * H;                    // 128*256
    unsigned short* bt_pl = bt_ph + 128 * 256;
    unsigned short* bt_1h = bt_pl + 128 * 256;                      // 128*128
    unsigned short* bt_1l = bt_1h + 128 * 128;
    unsigned short* bt_2h = bt_1l + 128 * 128;
    unsigned short* bt_2l = bt_2h + 128 * 128;
    unsigned short* bt_ch = bt_2l + 128 * 128;                      // 64*128
    unsigned short* bt_cl = bt_ch + 64 * 128;
    int*   cnt_in     = (int*)(bt_cl + 64 * 128);                   // N
    int*   row_start  = cnt_in + NN;                                // N
    float* rs_out     = (float*)(row_start + NN);                   // N
    float* rs_in      = rs_out + NN;                                // N
    int*   block_sums = (int*)(rs_in + NN);                         // 256
    int*   p_out      = block_sums + 256;                           // PSZ
    int*   csr_src    = p_out;                                      // E (p_out dead before fill)

    const int TB = 256;
    const int NB = (NN + 255) / 256;
    const dim3 ghist(NRG, CH);      // (8, 96) = 768 blocks; range -> XCD aligned
    // graph prepass (no global atomics)
    hist_node<<<ghist, 256, 0, stream>>>(src, p_out, E);
    hist_node<<<ghist, 256, 0, stream>>>(dst, p_in, E);
    merge_deg<<<(NN + TB - 1) / TB, TB, 0, stream>>>(p_out, p_in, cnt_in, rs_out, rs_in, NN);
    scan_partial<<<NB, 256, 0, stream>>>(cnt_in, row_start, block_sums, NN);
    scan_sums<<<1, 256, 0, stream>>>(block_sums, NB);
    scan_add<<<NB, 256, 0, stream>>>(row_start, block_sums, NN);
    fill_csr_part<<<ghist, 256, 0, stream>>>(src, dst, row_start, p_in, csr_src, E, NN);
    // weight prep (transpose + hi/lo split)
    prep_Bt<<<(128 * F + TB - 1) / TB, TB, 0, stream>>>(Wp, bt_ph, bt_pl, F, H, 128);
    prep_Bt<<<(128 * H + TB - 1) / TB, TB, 0, stream>>>(W1, bt_1h, bt_1l, H, H, 128);
    prep_Bt<<<(128 * H + TB - 1) / TB, TB, 0, stream>>>(W2, bt_2h, bt_2l, H, H, 128);
    prep_Bt<<<(64 * H + TB - 1) / TB, TB, 0, stream>>>(Wc, bt_ch, bt_cl, H, C, 64);

    const dim3 gg(1, (NN + 63) / 64);   // 782 blocks
    // projection: xbuf = n_feats @ Wp + bp            (fp32 out; p_in dead from here)
    mfma_gemm<0, 128><<<gg, 256, 0, stream>>>(n_feats, bt_ph, bt_pl, bp, nullptr,
                                              xbuf, nullptr, NN, H, F);
    // layer 1 GEMM: hbuf = bf16((xbuf @ W1) * rs_out)
    mfma_gemm<1, 128><<<gg, 256, 0, stream>>>(xbuf, bt_1h, bt_1l, nullptr, rs_out,
                                              nullptr, hbuf, NN, H, H);
    aggregate_bf16<<<(NN + 3) / 4, 256, 0, stream>>>((const unsigned int*)hbuf, csr_src,
                                                     row_start, cnt_in, rs_in, b1, xbuf, NN);
    // layer 2
    mfma_gemm<1, 128><<<gg, 256, 0, stream>>>(xbuf, bt_2h, bt_2l, nullptr, rs_out,
                                              nullptr, hbuf, NN, H, H);
    aggregate_bf16<<<(NN + 3) / 4, 256, 0, stream>>>((const unsigned int*)hbuf, csr_src,
                                                     row_start, cnt_in, rs_in, b2, xbuf, NN);
    // classifier: out = xbuf @ Wc + bc  (B padded to 64 cols, store-masked to 40)
    mfma_gemm<0, 64><<<gg, 256, 0, stream>>>(xbuf, bt_ch, bt_cl, bc, nullptr,
                                             out, nullptr, NN, C, H);
}

// Round 9
// 317.586 us; speedup vs baseline: 1.3184x; 1.0852x over previous
//
#include <hip/hip_runtime.h>

// Problem constants (from reference setup_inputs)
constexpr int NN = 50000;   // nodes
constexpr int H  = 128;     // hidden
constexpr int F  = 256;     // input features
constexpr int C  = 40;      // classes

// graph-prepass partitioning: 8 ranges of 6400 nodes, 96 chunks
// -> grid (8,96)=768 blocks; linear id = r + 8*c => range r pinned to XCD r.
constexpr int RSZ = 6400;
constexpr int NRG = 8;
constexpr int CH  = 96;

typedef short bf16x8 __attribute__((ext_vector_type(8)));
typedef short s16x4  __attribute__((ext_vector_type(4)));
typedef float f32x4  __attribute__((ext_vector_type(4)));

__device__ inline unsigned short f2bf(float f) {          // RNE fp32 -> bf16
    unsigned u = __float_as_uint(f);
    u += 0x7fff + ((u >> 16) & 1);
    return (unsigned short)(u >> 16);
}
__device__ inline float bf2f(unsigned short s) {
    return __uint_as_float(((unsigned)s) << 16);
}

// ------------------------------------------------ graph prepass (LDS histograms)
// Fused src+dst histogram for node range blockIdx.x, edge chunk blockIdx.y.
__global__ __launch_bounds__(256) void hist_both(
        const int* __restrict__ src, const int* __restrict__ dst,
        int* __restrict__ p_out, int* __restrict__ p_in, int E) {
    __shared__ int ho[RSZ];
    __shared__ int hi[RSZ];
    const int r = blockIdx.x;
    const int b = blockIdx.y;
    for (int i = threadIdx.x; i < RSZ; i += 256) { ho[i] = 0; hi[i] = 0; }
    __syncthreads();
    const int base = r * RSZ;
    const int CE = (E + CH - 1) / CH;
    const int e0 = b * CE, e1 = min(E, e0 + CE);
#pragma unroll 4
    for (int e = e0 + threadIdx.x; e < e1; e += 256) {
        int s = src[e], d = dst[e];
        unsigned so = (unsigned)(s - base);
        unsigned dо = (unsigned)(d - base);
        if (so < (unsigned)RSZ) atomicAdd(&ho[so], 1);
        if (dо < (unsigned)RSZ) atomicAdd(&hi[dо], 1);
    }
    __syncthreads();
    const long po = ((long)r * CH + b) * RSZ;
    for (int i = threadIdx.x; i < RSZ; i += 256) {
        p_out[po + i] = ho[i];
        p_in[po + i]  = hi[i];
    }
}

// Per-node merge: out-deg -> rs_out; in-deg -> cnt_in, rs_in;
// p_in converted in-place to exclusive prefix over chunks (per-chunk cursor bases).
__global__ __launch_bounds__(256) void merge_deg(
        const int* __restrict__ p_out, int* __restrict__ p_in,
        int* __restrict__ cnt_in, float* __restrict__ rs_out, float* __restrict__ rs_in,
        int n) {
    const int i = blockIdx.x * 256 + threadIdx.x;
    if (i >= n) return;
    const int r = i / RSZ, off = i % RSZ;
    const long pb = (long)r * CH * RSZ + off;
    int so = 0, si = 0;
#pragma unroll 4
    for (int b = 0; b < CH; b++) {
        so += p_out[pb + (long)b * RSZ];
        int v = p_in[pb + (long)b * RSZ];
        p_in[pb + (long)b * RSZ] = si;
        si += v;
    }
    cnt_in[i] = si;
    rs_out[i] = rsqrtf((float)max(so, 1));
    rs_in[i]  = rsqrtf((float)max(si, 1));
}

// CSR fill with LDS cursors — no global atomics. row_start holds the
// within-scanblock exclusive prefix; block_sums[node>>8] completes it.
__global__ __launch_bounds__(256) void fill_csr_part(
        const int* __restrict__ src, const int* __restrict__ dst,
        const int* __restrict__ row_start, const int* __restrict__ block_sums,
        const int* __restrict__ p_in,
        int* __restrict__ csr_src, int E, int n_nodes) {
    __shared__ int cur[RSZ];
    const int r = blockIdx.x;
    const int b = blockIdx.y;
    const int base = r * RSZ;
    const long po = ((long)r * CH + b) * RSZ;
    for (int i = threadIdx.x; i < RSZ; i += 256) {
        int node = base + i;
        int rs = (node < n_nodes) ? (row_start[node] + block_sums[node >> 8]) : 0;
        cur[i] = rs + p_in[po + i];
    }
    __syncthreads();
    const int CE = (E + CH - 1) / CH;
    const int e0 = b * CE, e1 = min(E, e0 + CE);
#pragma unroll 8
    for (int e = e0 + threadIdx.x; e < e1; e += 256) {
        int d = dst[e];
        unsigned dof = (unsigned)(d - base);
        if (dof < (unsigned)RSZ) {
            int pos = atomicAdd(&cur[dof], 1);   // LDS atomic
            csr_src[pos] = src[e];
        }
    }
}

// ------------------------------------------------ parallel exclusive scan (2 phases)
__global__ __launch_bounds__(256) void scan_partial(
        const int* __restrict__ cnt, int* __restrict__ excl,
        int* __restrict__ block_sums, int n) {
    __shared__ int sh[256];
    const int t = threadIdx.x;
    const int i = blockIdx.x * 256 + t;
    const int v = (i < n) ? cnt[i] : 0;
    sh[t] = v;
    __syncthreads();
#pragma unroll
    for (int off = 1; off < 256; off <<= 1) {
        int u = (t >= off) ? sh[t - off] : 0;
        __syncthreads();
        sh[t] += u;
        __syncthreads();
    }
    if (i < n) excl[i] = sh[t] - v;
    if (t == 255) block_sums[blockIdx.x] = sh[255];
}

__global__ __launch_bounds__(256) void scan_sums(int* __restrict__ block_sums, int nb) {
    __shared__ int sh[256];
    const int t = threadIdx.x;
    const int v = (t < nb) ? block_sums[t] : 0;
    sh[t] = v;
    __syncthreads();
#pragma unroll
    for (int off = 1; off < 256; off <<= 1) {
        int u = (t >= off) ? sh[t - off] : 0;
        __syncthreads();
        sh[t] += u;
        __syncthreads();
    }
    if (t < nb) block_sums[t] = sh[t] - v;
}

// ------------------------------------------------ weight prep (all 4, one launch)
__global__ __launch_bounds__(256) void prep_all(
        const float* __restrict__ Wp, const float* __restrict__ W1,
        const float* __restrict__ W2, const float* __restrict__ Wc,
        unsigned short* __restrict__ ph, unsigned short* __restrict__ pl,
        unsigned short* __restrict__ h1h, unsigned short* __restrict__ h1l,
        unsigned short* __restrict__ h2h, unsigned short* __restrict__ h2l,
        unsigned short* __restrict__ chh, unsigned short* __restrict__ cll) {
    int i = blockIdx.x * 256 + threadIdx.x;
    const float* W; unsigned short *Bh, *Bl; int K, N, NP, j;
    if (i < 32768)        { W = Wp; Bh = ph;  Bl = pl;  K = 256; N = 128; NP = 128; j = i; }
    else if (i < 49152)   { W = W1; Bh = h1h; Bl = h1l; K = 128; N = 128; NP = 128; j = i - 32768; }
    else if (i < 65536)   { W = W2; Bh = h2h; Bl = h2l; K = 128; N = 128; NP = 128; j = i - 49152; }
    else if (i < 73728)   { W = Wc; Bh = chh; Bl = cll; K = 128; N = 40;  NP = 64;  j = i - 65536; }
    else return;
    int n = j / K, k = j % K;
    float v = (n < N) ? W[(long)k * N + n] : 0.f;
    unsigned short hh = f2bf(v);
    unsigned short ll = f2bf(v - bf2f(hh));
    Bh[(long)n * K + k] = hh;
    Bl[(long)n * K + k] = ll;
}

// ------------------------------------------------ MFMA split-bf16 GEMM
// C = A(fp32,[M,K]) @ B(fp32,[K,Nout]) via hi/lo bf16 split (3 MFMA products).
// MODE 0: outf = acc + bias[gc]   (gc < Nout mask);  MODE 1: outh = bf16(acc*row_scale)
template<int MODE, int BN>
__global__ __launch_bounds__(256) void mfma_gemm(
        const float* __restrict__ A,
        const unsigned short* __restrict__ Bth, const unsigned short* __restrict__ Btl,
        const float* __restrict__ bias, const float* __restrict__ row_scale,
        float* __restrict__ outf, unsigned short* __restrict__ outh,
        int M, int Nout, int K) {
    constexpr int NT = BN / 64;
    __shared__ unsigned short As_h[4 * 65 * 8];
    __shared__ unsigned short As_l[4 * 65 * 8];
    __shared__ unsigned short Bs_h[4 * (BN + 1) * 8];
    __shared__ unsigned short Bs_l[4 * (BN + 1) * 8];

    const int tid  = threadIdx.x;
    const int wave = tid >> 6;
    const int lane = tid & 63;
    const int quad = lane >> 4;
    const int lr   = lane & 15;
    const int row0 = blockIdx.y * 64;
    const int wn0  = wave * (BN / 4);

    f32x4 acc[4][NT];
#pragma unroll
    for (int mt = 0; mt < 4; mt++)
#pragma unroll
        for (int nt = 0; nt < NT; nt++)
            acc[mt][nt] = (f32x4){0.f, 0.f, 0.f, 0.f};

    for (int k0 = 0; k0 < K; k0 += 32) {
#pragma unroll
        for (int r = 0; r < 2; r++) {
            int c   = tid + 256 * r;
            int row = c >> 3;
            int k4f = c & 7;
            int gr  = row0 + row;
            float4 v = make_float4(0.f, 0.f, 0.f, 0.f);
            if (gr < M) v = *(const float4*)&A[(long)gr * K + k0 + k4f * 4];
            unsigned short h0 = f2bf(v.x), h1 = f2bf(v.y), h2 = f2bf(v.z), h3 = f2bf(v.w);
            unsigned short l0 = f2bf(v.x - bf2f(h0));
            unsigned short l1 = f2bf(v.y - bf2f(h1));
            unsigned short l2 = f2bf(v.z - bf2f(h2));
            unsigned short l3 = f2bf(v.w - bf2f(h3));
            int base = (k4f >> 1) * 520 + row * 8 + (k4f & 1) * 4;
            s16x4 hv; hv[0] = (short)h0; hv[1] = (short)h1; hv[2] = (short)h2; hv[3] = (short)h3;
            s16x4 lv; lv[0] = (short)l0; lv[1] = (short)l1; lv[2] = (short)l2; lv[3] = (short)l3;
            *(s16x4*)&As_h[base] = hv;
            *(s16x4*)&As_l[base] = lv;
        }
        for (int c = tid; c < BN * 4; c += 256) {
            int n  = c >> 2;
            int k4 = c & 3;
            long off = (long)n * K + k0 + k4 * 8;
            uint4 vh = *(const uint4*)&Bth[off];
            uint4 vl = *(const uint4*)&Btl[off];
            int bbase = k4 * (BN + 1) * 8 + n * 8;
            *(uint4*)&Bs_h[bbase] = vh;
            *(uint4*)&Bs_l[bbase] = vl;
        }
        __syncthreads();

        bf16x8 ah[4], al[4], bh[NT], bl[NT];
#pragma unroll
        for (int mt = 0; mt < 4; mt++) {
            int ab = quad * 520 + (mt * 16 + lr) * 8;
            ah[mt] = *(const bf16x8*)&As_h[ab];
            al[mt] = *(const bf16x8*)&As_l[ab];
        }
#pragma unroll
        for (int nt = 0; nt < NT; nt++) {
            int bb = quad * (BN + 1) * 8 + (wn0 + nt * 16 + lr) * 8;
            bh[nt] = *(const bf16x8*)&Bs_h[bb];
            bl[nt] = *(const bf16x8*)&Bs_l[bb];
        }
#pragma unroll
        for (int mt = 0; mt < 4; mt++)
#pragma unroll
            for (int nt = 0; nt < NT; nt++) {
                acc[mt][nt] = __builtin_amdgcn_mfma_f32_16x16x32_bf16(ah[mt], bh[nt], acc[mt][nt], 0, 0, 0);
                acc[mt][nt] = __builtin_amdgcn_mfma_f32_16x16x32_bf16(al[mt], bh[nt], acc[mt][nt], 0, 0, 0);
                acc[mt][nt] = __builtin_amdgcn_mfma_f32_16x16x32_bf16(ah[mt], bl[nt], acc[mt][nt], 0, 0, 0);
            }
        __syncthreads();
    }

#pragma unroll
    for (int mt = 0; mt < 4; mt++) {
#pragma unroll
        for (int nt = 0; nt < NT; nt++) {
            int gc = wn0 + nt * 16 + lr;
#pragma unroll
            for (int r = 0; r < 4; r++) {
                int gr = row0 + mt * 16 + quad * 4 + r;
                if (gr >= M) continue;
                float v = acc[mt][nt][r];
                if (MODE == 0) {
                    if (gc < Nout) outf[(long)gr * Nout + gc] = v + bias[gc];
                } else {
                    v *= row_scale[gr];
                    outh[(long)gr * Nout + gc] = f2bf(v);
                }
            }
        }
    }
}

// ---------------------------------------------------------------- aggregation (bf16 h)
// out[v,:] = relu( rs_in[v] * sum_{s in row(v)} h[s,:] + bias[:] )
// Wave handles 4 neighbors at once: lane-group g (16 lanes) reads neighbor i0+g's
// full 256 B row as uint4; cross-group sum via shfl_xor(16/32) at the end.
__global__ __launch_bounds__(256) void aggregate_bf16(
        const uint4* __restrict__ h4, const int* __restrict__ csr_src,
        const int* __restrict__ row_start, const int* __restrict__ block_sums,
        const int* __restrict__ cnt_in,
        const float* __restrict__ rs_in, const float* __restrict__ bias,
        float* __restrict__ out, int nodes) {
    const int wave = threadIdx.x >> 6;
    const int lane = threadIdx.x & 63;
    const int grp  = lane >> 4;        // 0..3 = neighbor slot
    const int sl   = lane & 15;        // uint4 index in row
    const int v = blockIdx.x * 4 + wave;
    if (v >= nodes) return;
    const int s0  = row_start[v] + block_sums[v >> 8];
    const int cnt = cnt_in[v];

    float ax0 = 0.f, ay0 = 0.f, ax1 = 0.f, ay1 = 0.f;
    float ax2 = 0.f, ay2 = 0.f, ax3 = 0.f, ay3 = 0.f;
    int i0 = 0;
    for (; i0 + 8 <= cnt; i0 += 8) {               // 8 neighbors in flight
        int sA = csr_src[s0 + i0 + grp];
        int sB = csr_src[s0 + i0 + 4 + grp];
        uint4 uA = h4[(long)sA * 16 + sl];
        uint4 uB = h4[(long)sB * 16 + sl];
        ax0 += __uint_as_float(uA.x << 16) + __uint_as_float(uB.x << 16);
        ay0 += __uint_as_float(uA.x & 0xffff0000u) + __uint_as_float(uB.x & 0xffff0000u);
        ax1 += __uint_as_float(uA.y << 16) + __uint_as_float(uB.y << 16);
        ay1 += __uint_as_float(uA.y & 0xffff0000u) + __uint_as_float(uB.y & 0xffff0000u);
        ax2 += __uint_as_float(uA.z << 16) + __uint_as_float(uB.z << 16);
        ay2 += __uint_as_float(uA.z & 0xffff0000u) + __uint_as_float(uB.z & 0xffff0000u);
        ax3 += __uint_as_float(uA.w << 16) + __uint_as_float(uB.w << 16);
        ay3 += __uint_as_float(uA.w & 0xffff0000u) + __uint_as_float(uB.w & 0xffff0000u);
    }
    for (; i0 + 4 <= cnt; i0 += 4) {
        int s = csr_src[s0 + i0 + grp];
        uint4 u = h4[(long)s * 16 + sl];
        ax0 += __uint_as_float(u.x << 16); ay0 += __uint_as_float(u.x & 0xffff0000u);
        ax1 += __uint_as_float(u.y << 16); ay1 += __uint_as_float(u.y & 0xffff0000u);
        ax2 += __uint_as_float(u.z << 16); ay2 += __uint_as_float(u.z & 0xffff0000u);
        ax3 += __uint_as_float(u.w << 16); ay3 += __uint_as_float(u.w & 0xffff0000u);
    }
    if (i0 + grp < cnt) {                          // 0..3 tail neighbors
        int s = csr_src[s0 + i0 + grp];
        uint4 u = h4[(long)s * 16 + sl];
        ax0 += __uint_as_float(u.x << 16); ay0 += __uint_as_float(u.x & 0xffff0000u);
        ax1 += __uint_as_float(u.y << 16); ay1 += __uint_as_float(u.y & 0xffff0000u);
        ax2 += __uint_as_float(u.z << 16); ay2 += __uint_as_float(u.z & 0xffff0000u);
        ax3 += __uint_as_float(u.w << 16); ay3 += __uint_as_float(u.w & 0xffff0000u);
    }
    // sum across the 4 lane-groups (lanes differing in bits 4,5)
    ax0 += __shfl_xor(ax0, 16); ay0 += __shfl_xor(ay0, 16);
    ax1 += __shfl_xor(ax1, 16); ay1 += __shfl_xor(ay1, 16);
    ax2 += __shfl_xor(ax2, 16); ay2 += __shfl_xor(ay2, 16);
    ax3 += __shfl_xor(ax3, 16); ay3 += __shfl_xor(ay3, 16);
    ax0 += __shfl_xor(ax0, 32); ay0 += __shfl_xor(ay0, 32);
    ax1 += __shfl_xor(ax1, 32); ay1 += __shfl_xor(ay1, 32);
    ax2 += __shfl_xor(ax2, 32); ay2 += __shfl_xor(ay2, 32);
    ax3 += __shfl_xor(ax3, 32); ay3 += __shfl_xor(ay3, 32);

    if (grp == 0) {                                // lanes 0..15 store the row
        const float rs = rs_in[v];
        const float2 b0 = ((const float2*)bias)[sl * 4 + 0];
        const float2 b1 = ((const float2*)bias)[sl * 4 + 1];
        const float2 b2 = ((const float2*)bias)[sl * 4 + 2];
        const float2 b3 = ((const float2*)bias)[sl * 4 + 3];
        float4 o0, o1;
        o0.x = fmaxf(ax0 * rs + b0.x, 0.f); o0.y = fmaxf(ay0 * rs + b0.y, 0.f);
        o0.z = fmaxf(ax1 * rs + b1.x, 0.f); o0.w = fmaxf(ay1 * rs + b1.y, 0.f);
        o1.x = fmaxf(ax2 * rs + b2.x, 0.f); o1.y = fmaxf(ay2 * rs + b2.y, 0.f);
        o1.z = fmaxf(ax3 * rs + b3.x, 0.f); o1.w = fmaxf(ay3 * rs + b3.y, 0.f);
        float4* orow = (float4*)&out[(long)v * H];
        orow[sl * 2 + 0] = o0;
        orow[sl * 2 + 1] = o1;
    }
}

// ---------------------------------------------------------------- launch
extern "C" void kernel_launch(void* const* d_in, const int* in_sizes, int n_in,
                              void* d_out, int out_size, void* d_ws, size_t ws_size,
                              hipStream_t stream) {
    const float* n_feats = (const float*)d_in[0];
    const int*   src     = (const int*)d_in[1];
    const int*   dst     = (const int*)d_in[2];
    const float* Wp      = (const float*)d_in[3];
    const float* bp      = (const float*)d_in[4];
    const float* W1      = (const float*)d_in[5];
    const float* b1      = (const float*)d_in[6];
    const float* W2      = (const float*)d_in[7];
    const float* b2      = (const float*)d_in[8];
    const float* Wc      = (const float*)d_in[9];
    const float* bc      = (const float*)d_in[10];
    float* out = (float*)d_out;
    const int E = in_sizes[1];

    const long PSZ = (long)NRG * CH * RSZ;     // partials: 4,915,200 ints (19.66 MB)

    // workspace layout (aliasing: p_in <-> xbuf, p_out <-> csr_src)
    char* ws = (char*)d_ws;
    float*          xbuf  = (float*)ws;                             // NN*128 fp32 (25.6 MB)
    int*            p_in  = (int*)xbuf;                             // PSZ (dead before xbuf written)
    unsigned short* hbuf  = (unsigned short*)(xbuf + (long)NN * H); // NN*128 bf16 (12.8 MB)
    unsigned short* bt_ph = hbuf + (long)NN * H;                    // 128*256
    unsigned short* bt_pl = bt_ph + 128 * 256;
    unsigned short* bt_1h = bt_pl + 128 * 256;                      // 128*128
    unsigned short* bt_1l = bt_1h + 128 * 128;
    unsigned short* bt_2h = bt_1l + 128 * 128;
    unsigned short* bt_2l = bt_2h + 128 * 128;
    unsigned short* bt_ch = bt_2l + 128 * 128;                      // 64*128
    unsigned short* bt_cl = bt_ch + 64 * 128;
    int*   cnt_in     = (int*)(bt_cl + 64 * 128);                   // N
    int*   row_start  = cnt_in + NN;                                // N (within-block excl)
    float* rs_out     = (float*)(row_start + NN);                   // N
    float* rs_in      = rs_out + NN;                                // N
    int*   block_sums = (int*)(rs_in + NN);                         // 256
    int*   p_out      = block_sums + 256;                           // PSZ
    int*   csr_src    = p_out;                                      // E (p_out dead before fill)

    const int TB = 256;
    const int NB = (NN + 255) / 256;    // 196
    const dim3 ghist(NRG, CH);          // (8, 96) = 768 blocks; range -> XCD aligned
    // graph prepass (no global atomics)
    hist_both<<<ghist, 256, 0, stream>>>(src, dst, p_out, p_in, E);
    merge_deg<<<(NN + TB - 1) / TB, TB, 0, stream>>>(p_out, p_in, cnt_in, rs_out, rs_in, NN);
    scan_partial<<<NB, 256, 0, stream>>>(cnt_in, row_start, block_sums, NN);
    scan_sums<<<1, 256, 0, stream>>>(block_sums, NB);
    fill_csr_part<<<ghist, 256, 0, stream>>>(src, dst, row_start, block_sums, p_in,
                                             csr_src, E, NN);
    // weight prep (transpose + hi/lo split), one launch
    prep_all<<<288, 256, 0, stream>>>(Wp, W1, W2, Wc, bt_ph, bt_pl,
                                      bt_1h, bt_1l, bt_2h, bt_2l, bt_ch, bt_cl);

    const dim3 gg(1, (NN + 63) / 64);   // 782 blocks
    // projection: xbuf = n_feats @ Wp + bp            (fp32 out; p_in dead from here)
    mfma_gemm<0, 128><<<gg, 256, 0, stream>>>(n_feats, bt_ph, bt_pl, bp, nullptr,
                                              xbuf, nullptr, NN, H, F);
    // layer 1 GEMM: hbuf = bf16((xbuf @ W1) * rs_out)
    mfma_gemm<1, 128><<<gg, 256, 0, stream>>>(xbuf, bt_1h, bt_1l, nullptr, rs_out,
                                              nullptr, hbuf, NN, H, H);
    aggregate_bf16<<<(NN + 3) / 4, 256, 0, stream>>>((const uint4*)hbuf, csr_src,
                                                     row_start, block_sums, cnt_in,
                                                     rs_in, b1, xbuf, NN);
    // layer 2
    mfma_gemm<1, 128><<<gg, 256, 0, stream>>>(xbuf, bt_2h, bt_2l, nullptr, rs_out,
                                              nullptr, hbuf, NN, H, H);
    aggregate_bf16<<<(NN + 3) / 4, 256, 0, stream>>>((const uint4*)hbuf, csr_src,
                                                     row_start, block_sums, cnt_in,
                                                     rs_in, b2, xbuf, NN);
    // classifier: out = xbuf @ Wc + bc  (B padded to 64 cols, store-masked to 40)
    mfma_gemm<0, 64><<<gg, 256, 0, stream>>>(xbuf, bt_ch, bt_cl, bc, nullptr,
                                             out, nullptr, NN, C, H);
}

// Round 10
// 308.937 us; speedup vs baseline: 1.3553x; 1.0280x over previous
//
#include <hip/hip_runtime.h>

// Problem constants (from reference setup_inputs)
constexpr int NN = 50000;   // nodes
constexpr int H  = 128;     // hidden
constexpr int F  = 256;     // input features
constexpr int C  = 40;      // classes

// graph-prepass partitioning: 8 ranges of 6400 nodes, 96 chunks
// -> grid (8,96)=768 blocks; linear id = r + 8*c => range r pinned to XCD r.
constexpr int RSZ = 6400;
constexpr int NRG = 8;
constexpr int CH  = 96;

typedef short bf16x8 __attribute__((ext_vector_type(8)));
typedef short s16x4  __attribute__((ext_vector_type(4)));
typedef float f32x4  __attribute__((ext_vector_type(4)));

__device__ inline unsigned short f2bf(float f) {          // RNE fp32 -> bf16
    unsigned u = __float_as_uint(f);
    u += 0x7fff + ((u >> 16) & 1);
    return (unsigned short)(u >> 16);
}
__device__ inline float bf2f(unsigned short s) {
    return __uint_as_float(((unsigned)s) << 16);
}

// ------------------------------------------------ graph prepass (LDS histograms)
// Fused src+dst histogram; partials stored as u16 (max count << 65536),
// packed two-per-u32 for the stores.
__global__ __launch_bounds__(256) void hist_both(
        const int* __restrict__ src, const int* __restrict__ dst,
        unsigned short* __restrict__ p_out, unsigned short* __restrict__ p_in, int E) {
    __shared__ int ho[RSZ];
    __shared__ int hi[RSZ];
    const int r = blockIdx.x;
    const int b = blockIdx.y;
    for (int i = threadIdx.x; i < RSZ; i += 256) { ho[i] = 0; hi[i] = 0; }
    __syncthreads();
    const int base = r * RSZ;
    const int CE = (E + CH - 1) / CH;
    const int e0 = b * CE, e1 = min(E, e0 + CE);
#pragma unroll 4
    for (int e = e0 + threadIdx.x; e < e1; e += 256) {
        int s = src[e], d = dst[e];
        unsigned so = (unsigned)(s - base);
        unsigned dо = (unsigned)(d - base);
        if (so < (unsigned)RSZ) atomicAdd(&ho[so], 1);
        if (dо < (unsigned)RSZ) atomicAdd(&hi[dо], 1);
    }
    __syncthreads();
    const long po = ((long)r * CH + b) * RSZ;   // even (RSZ even)
    unsigned* o32 = (unsigned*)&p_out[po];
    unsigned* i32 = (unsigned*)&p_in[po];
    for (int i = threadIdx.x; i < RSZ / 2; i += 256) {
        o32[i] = (unsigned)ho[2 * i] | ((unsigned)ho[2 * i + 1] << 16);
        i32[i] = (unsigned)hi[2 * i] | ((unsigned)hi[2 * i + 1] << 16);
    }
}

// Fused per-node merge + in-block scan.
// Per node: out-deg -> rs_out; in-deg -> cnt_in, rs_in; p_in -> exclusive
// chunk-prefix (u16). Then Hillis-Steele over the block's 256 cnt values ->
// row_start (within-block exclusive) + block_sums[blockIdx.x].
__global__ __launch_bounds__(256) void merge_scan(
        const unsigned short* __restrict__ p_out, unsigned short* __restrict__ p_in,
        int* __restrict__ cnt_in, float* __restrict__ rs_out, float* __restrict__ rs_in,
        int* __restrict__ row_start, int* __restrict__ block_sums, int n) {
    __shared__ int sh[256];
    const int t = threadIdx.x;
    const int i = blockIdx.x * 256 + t;
    int si = 0;
    if (i < n) {
        const int r = i / RSZ, off = i % RSZ;
        const long pb = (long)r * CH * RSZ + off;
        int so = 0;
#pragma unroll 4
        for (int b = 0; b < CH; b++) {
            so += p_out[pb + (long)b * RSZ];
            int v = p_in[pb + (long)b * RSZ];
            p_in[pb + (long)b * RSZ] = (unsigned short)si;
            si += v;
        }
        cnt_in[i] = si;
        rs_out[i] = rsqrtf((float)max(so, 1));
        rs_in[i]  = rsqrtf((float)max(si, 1));
    }
    sh[t] = si;
    __syncthreads();
#pragma unroll
    for (int off = 1; off < 256; off <<= 1) {
        int u = (t >= off) ? sh[t - off] : 0;
        __syncthreads();
        sh[t] += u;
        __syncthreads();
    }
    if (i < n) row_start[i] = sh[t] - si;
    if (t == 255) block_sums[blockIdx.x] = sh[255];
}

// Block 0: exclusive scan of block_sums. Blocks 1..: weight transpose+split.
__global__ __launch_bounds__(256) void scan_sums_prep(
        int* __restrict__ block_sums, int nb,
        const float* __restrict__ Wp, const float* __restrict__ W1,
        const float* __restrict__ W2, const float* __restrict__ Wc,
        unsigned short* __restrict__ ph, unsigned short* __restrict__ pl,
        unsigned short* __restrict__ h1h, unsigned short* __restrict__ h1l,
        unsigned short* __restrict__ h2h, unsigned short* __restrict__ h2l,
        unsigned short* __restrict__ chh, unsigned short* __restrict__ cll) {
    const int t = threadIdx.x;
    if (blockIdx.x == 0) {
        __shared__ int sh[256];
        const int v = (t < nb) ? block_sums[t] : 0;
        sh[t] = v;
        __syncthreads();
#pragma unroll
        for (int off = 1; off < 256; off <<= 1) {
            int u = (t >= off) ? sh[t - off] : 0;
            __syncthreads();
            sh[t] += u;
            __syncthreads();
        }
        if (t < nb) block_sums[t] = sh[t] - v;
        return;
    }
    int i = (blockIdx.x - 1) * 256 + t;
    const float* W; unsigned short *Bh, *Bl; int K, N, NP, j;
    if (i < 32768)        { W = Wp; Bh = ph;  Bl = pl;  K = 256; N = 128; NP = 128; j = i; }
    else if (i < 49152)   { W = W1; Bh = h1h; Bl = h1l; K = 128; N = 128; NP = 128; j = i - 32768; }
    else if (i < 65536)   { W = W2; Bh = h2h; Bl = h2l; K = 128; N = 128; NP = 128; j = i - 49152; }
    else if (i < 73728)   { W = Wc; Bh = chh; Bl = cll; K = 128; N = 40;  NP = 64;  j = i - 65536; }
    else return;
    int n = j / K, k = j % K;
    float v = (n < N) ? W[(long)k * N + n] : 0.f;
    unsigned short hh = f2bf(v);
    unsigned short ll = f2bf(v - bf2f(hh));
    Bh[(long)n * K + k] = hh;
    Bl[(long)n * K + k] = ll;
}

// CSR fill with LDS cursors — no global atomics. row_start holds the
// within-scanblock exclusive prefix; block_sums[node>>8] completes it.
__global__ __launch_bounds__(256) void fill_csr_part(
        const int* __restrict__ src, const int* __restrict__ dst,
        const int* __restrict__ row_start, const int* __restrict__ block_sums,
        const unsigned short* __restrict__ p_in,
        int* __restrict__ csr_src, int E, int n_nodes) {
    __shared__ int cur[RSZ];
    const int r = blockIdx.x;
    const int b = blockIdx.y;
    const int base = r * RSZ;
    const long po = ((long)r * CH + b) * RSZ;
    for (int i = threadIdx.x; i < RSZ; i += 256) {
        int node = base + i;
        int rs = (node < n_nodes) ? (row_start[node] + block_sums[node >> 8]) : 0;
        cur[i] = rs + (int)p_in[po + i];
    }
    __syncthreads();
    const int CE = (E + CH - 1) / CH;
    const int e0 = b * CE, e1 = min(E, e0 + CE);
#pragma unroll 8
    for (int e = e0 + threadIdx.x; e < e1; e += 256) {
        int d = dst[e];
        unsigned dof = (unsigned)(d - base);
        if (dof < (unsigned)RSZ) {
            int pos = atomicAdd(&cur[dof], 1);   // LDS atomic
            csr_src[pos] = src[e];
        }
    }
}

// ------------------------------------------------ MFMA split-bf16 GEMM
// C = A(fp32,[M,K]) @ B(fp32,[K,Nout]) via hi/lo bf16 split (3 MFMA products).
// MODE 0: outf = acc + bias[gc]   (gc < Nout mask);  MODE 1: outh = bf16(acc*row_scale)
template<int MODE, int BN>
__global__ __launch_bounds__(256) void mfma_gemm(
        const float* __restrict__ A,
        const unsigned short* __restrict__ Bth, const unsigned short* __restrict__ Btl,
        const float* __restrict__ bias, const float* __restrict__ row_scale,
        float* __restrict__ outf, unsigned short* __restrict__ outh,
        int M, int Nout, int K) {
    constexpr int NT = BN / 64;
    __shared__ unsigned short As_h[4 * 65 * 8];
    __shared__ unsigned short As_l[4 * 65 * 8];
    __shared__ unsigned short Bs_h[4 * (BN + 1) * 8];
    __shared__ unsigned short Bs_l[4 * (BN + 1) * 8];

    const int tid  = threadIdx.x;
    const int wave = tid >> 6;
    const int lane = tid & 63;
    const int quad = lane >> 4;
    const int lr   = lane & 15;
    const int row0 = blockIdx.y * 64;
    const int wn0  = wave * (BN / 4);

    f32x4 acc[4][NT];
#pragma unroll
    for (int mt = 0; mt < 4; mt++)
#pragma unroll
        for (int nt = 0; nt < NT; nt++)
            acc[mt][nt] = (f32x4){0.f, 0.f, 0.f, 0.f};

    for (int k0 = 0; k0 < K; k0 += 32) {
#pragma unroll
        for (int r = 0; r < 2; r++) {
            int c   = tid + 256 * r;
            int row = c >> 3;
            int k4f = c & 7;
            int gr  = row0 + row;
            float4 v = make_float4(0.f, 0.f, 0.f, 0.f);
            if (gr < M) v = *(const float4*)&A[(long)gr * K + k0 + k4f * 4];
            unsigned short h0 = f2bf(v.x), h1 = f2bf(v.y), h2 = f2bf(v.z), h3 = f2bf(v.w);
            unsigned short l0 = f2bf(v.x - bf2f(h0));
            unsigned short l1 = f2bf(v.y - bf2f(h1));
            unsigned short l2 = f2bf(v.z - bf2f(h2));
            unsigned short l3 = f2bf(v.w - bf2f(h3));
            int base = (k4f >> 1) * 520 + row * 8 + (k4f & 1) * 4;
            s16x4 hv; hv[0] = (short)h0; hv[1] = (short)h1; hv[2] = (short)h2; hv[3] = (short)h3;
            s16x4 lv; lv[0] = (short)l0; lv[1] = (short)l1; lv[2] = (short)l2; lv[3] = (short)l3;
            *(s16x4*)&As_h[base] = hv;
            *(s16x4*)&As_l[base] = lv;
        }
        for (int c = tid; c < BN * 4; c += 256) {
            int n  = c >> 2;
            int k4 = c & 3;
            long off = (long)n * K + k0 + k4 * 8;
            uint4 vh = *(const uint4*)&Bth[off];
            uint4 vl = *(const uint4*)&Btl[off];
            int bbase = k4 * (BN + 1) * 8 + n * 8;
            *(uint4*)&Bs_h[bbase] = vh;
            *(uint4*)&Bs_l[bbase] = vl;
        }
        __syncthreads();

        bf16x8 ah[4], al[4], bh[NT], bl[NT];
#pragma unroll
        for (int mt = 0; mt < 4; mt++) {
            int ab = quad * 520 + (mt * 16 + lr) * 8;
            ah[mt] = *(const bf16x8*)&As_h[ab];
            al[mt] = *(const bf16x8*)&As_l[ab];
        }
#pragma unroll
        for (int nt = 0; nt < NT; nt++) {
            int bb = quad * (BN + 1) * 8 + (wn0 + nt * 16 + lr) * 8;
            bh[nt] = *(const bf16x8*)&Bs_h[bb];
            bl[nt] = *(const bf16x8*)&Bs_l[bb];
        }
#pragma unroll
        for (int mt = 0; mt < 4; mt++)
#pragma unroll
            for (int nt = 0; nt < NT; nt++) {
                acc[mt][nt] = __builtin_amdgcn_mfma_f32_16x16x32_bf16(ah[mt], bh[nt], acc[mt][nt], 0, 0, 0);
                acc[mt][nt] = __builtin_amdgcn_mfma_f32_16x16x32_bf16(al[mt], bh[nt], acc[mt][nt], 0, 0, 0);
                acc[mt][nt] = __builtin_amdgcn_mfma_f32_16x16x32_bf16(ah[mt], bl[nt], acc[mt][nt], 0, 0, 0);
            }
        __syncthreads();
    }

#pragma unroll
    for (int mt = 0; mt < 4; mt++) {
#pragma unroll
        for (int nt = 0; nt < NT; nt++) {
            int gc = wn0 + nt * 16 + lr;
#pragma unroll
            for (int r = 0; r < 4; r++) {
                int gr = row0 + mt * 16 + quad * 4 + r;
                if (gr >= M) continue;
                float v = acc[mt][nt][r];
                if (MODE == 0) {
                    if (gc < Nout) outf[(long)gr * Nout + gc] = v + bias[gc];
                } else {
                    v *= row_scale[gr];
                    outh[(long)gr * Nout + gc] = f2bf(v);
                }
            }
        }
    }
}

// ---------------------------------------------------------------- aggregation (bf16 h)
// out[v,:] = relu( rs_in[v] * sum_{s in row(v)} h[s,:] + bias[:] )
// Wave handles 4 neighbors at once: lane-group g (16 lanes) reads neighbor i0+g's
// full 256 B row as uint4; cross-group sum via shfl_xor(16/32) at the end.
__global__ __launch_bounds__(256) void aggregate_bf16(
        const uint4* __restrict__ h4, const int* __restrict__ csr_src,
        const int* __restrict__ row_start, const int* __restrict__ block_sums,
        const int* __restrict__ cnt_in,
        const float* __restrict__ rs_in, const float* __restrict__ bias,
        float* __restrict__ out, int nodes) {
    const int wave = threadIdx.x >> 6;
    const int lane = threadIdx.x & 63;
    const int grp  = lane >> 4;        // 0..3 = neighbor slot
    const int sl   = lane & 15;        // uint4 index in row
    const int v = blockIdx.x * 4 + wave;
    if (v >= nodes) return;
    const int s0  = row_start[v] + block_sums[v >> 8];
    const int cnt = cnt_in[v];

    float ax0 = 0.f, ay0 = 0.f, ax1 = 0.f, ay1 = 0.f;
    float ax2 = 0.f, ay2 = 0.f, ax3 = 0.f, ay3 = 0.f;
    int i0 = 0;
    for (; i0 + 8 <= cnt; i0 += 8) {               // 8 neighbors in flight
        int sA = csr_src[s0 + i0 + grp];
        int sB = csr_src[s0 + i0 + 4 + grp];
        uint4 uA = h4[(long)sA * 16 + sl];
        uint4 uB = h4[(long)sB * 16 + sl];
        ax0 += __uint_as_float(uA.x << 16) + __uint_as_float(uB.x << 16);
        ay0 += __uint_as_float(uA.x & 0xffff0000u) + __uint_as_float(uB.x & 0xffff0000u);
        ax1 += __uint_as_float(uA.y << 16) + __uint_as_float(uB.y << 16);
        ay1 += __uint_as_float(uA.y & 0xffff0000u) + __uint_as_float(uB.y & 0xffff0000u);
        ax2 += __uint_as_float(uA.z << 16) + __uint_as_float(uB.z << 16);
        ay2 += __uint_as_float(uA.z & 0xffff0000u) + __uint_as_float(uB.z & 0xffff0000u);
        ax3 += __uint_as_float(uA.w << 16) + __uint_as_float(uB.w << 16);
        ay3 += __uint_as_float(uA.w & 0xffff0000u) + __uint_as_float(uB.w & 0xffff0000u);
    }
    for (; i0 + 4 <= cnt; i0 += 4) {
        int s = csr_src[s0 + i0 + grp];
        uint4 u = h4[(long)s * 16 + sl];
        ax0 += __uint_as_float(u.x << 16); ay0 += __uint_as_float(u.x & 0xffff0000u);
        ax1 += __uint_as_float(u.y << 16); ay1 += __uint_as_float(u.y & 0xffff0000u);
        ax2 += __uint_as_float(u.z << 16); ay2 += __uint_as_float(u.z & 0xffff0000u);
        ax3 += __uint_as_float(u.w << 16); ay3 += __uint_as_float(u.w & 0xffff0000u);
    }
    if (i0 + grp < cnt) {                          // 0..3 tail neighbors
        int s = csr_src[s0 + i0 + grp];
        uint4 u = h4[(long)s * 16 + sl];
        ax0 += __uint_as_float(u.x << 16); ay0 += __uint_as_float(u.x & 0xffff0000u);
        ax1 += __uint_as_float(u.y << 16); ay1 += __uint_as_float(u.y & 0xffff0000u);
        ax2 += __uint_as_float(u.z << 16); ay2 += __uint_as_float(u.z & 0xffff0000u);
        ax3 += __uint_as_float(u.w << 16); ay3 += __uint_as_float(u.w & 0xffff0000u);
    }
    // sum across the 4 lane-groups (lanes differing in bits 4,5)
    ax0 += __shfl_xor(ax0, 16); ay0 += __shfl_xor(ay0, 16);
    ax1 += __shfl_xor(ax1, 16); ay1 += __shfl_xor(ay1, 16);
    ax2 += __shfl_xor(ax2, 16); ay2 += __shfl_xor(ay2, 16);
    ax3 += __shfl_xor(ax3, 16); ay3 += __shfl_xor(ay3, 16);
    ax0 += __shfl_xor(ax0, 32); ay0 += __shfl_xor(ay0, 32);
    ax1 += __shfl_xor(ax1, 32); ay1 += __shfl_xor(ay1, 32);
    ax2 += __shfl_xor(ax2, 32); ay2 += __shfl_xor(ay2, 32);
    ax3 += __shfl_xor(ax3, 32); ay3 += __shfl_xor(ay3, 32);

    if (grp == 0) {                                // lanes 0..15 store the row
        const float rs = rs_in[v];
        const float2 b0 = ((const float2*)bias)[sl * 4 + 0];
        const float2 b1 = ((const float2*)bias)[sl * 4 + 1];
        const float2 b2 = ((const float2*)bias)[sl * 4 + 2];
        const float2 b3 = ((const float2*)bias)[sl * 4 + 3];
        float4 o0, o1;
        o0.x = fmaxf(ax0 * rs + b0.x, 0.f); o0.y = fmaxf(ay0 * rs + b0.y, 0.f);
        o0.z = fmaxf(ax1 * rs + b1.x, 0.f); o0.w = fmaxf(ay1 * rs + b1.y, 0.f);
        o1.x = fmaxf(ax2 * rs + b2.x, 0.f); o1.y = fmaxf(ay2 * rs + b2.y, 0.f);
        o1.z = fmaxf(ax3 * rs + b3.x, 0.f); o1.w = fmaxf(ay3 * rs + b3.y, 0.f);
        float4* orow = (float4*)&out[(long)v * H];
        orow[sl * 2 + 0] = o0;
        orow[sl * 2 + 1] = o1;
    }
}

// ---------------------------------------------------------------- launch
extern "C" void kernel_launch(void* const* d_in, const int* in_sizes, int n_in,
                              void* d_out, int out_size, void* d_ws, size_t ws_size,
                              hipStream_t stream) {
    const float* n_feats = (const float*)d_in[0];
    const int*   src     = (const int*)d_in[1];
    const int*   dst     = (const int*)d_in[2];
    const float* Wp      = (const float*)d_in[3];
    const float* bp      = (const float*)d_in[4];
    const float* W1      = (const float*)d_in[5];
    const float* b1      = (const float*)d_in[6];
    const float* W2      = (const float*)d_in[7];
    const float* b2      = (const float*)d_in[8];
    const float* Wc      = (const float*)d_in[9];
    const float* bc      = (const float*)d_in[10];
    float* out = (float*)d_out;
    const int E = in_sizes[1];

    const long PSZ = (long)NRG * CH * RSZ;     // partials: 4,915,200 u16 (9.83 MB)

    // workspace layout (aliasing: p_in <-> xbuf, p_out <-> csr_src)
    char* ws = (char*)d_ws;
    float*          xbuf  = (float*)ws;                             // NN*128 fp32 (25.6 MB)
    unsigned short* p_in  = (unsigned short*)xbuf;                  // PSZ u16 (dead before xbuf written)
    unsigned short* hbuf  = (unsigned short*)(xbuf + (long)NN * H); // NN*128 bf16 (12.8 MB)
    unsigned short* bt_ph = hbuf + (long)NN * H;                    // 128*256
    unsigned short* bt_pl = bt_ph + 128 * 256;
    unsigned short* bt_1h = bt_pl + 128 * 256;                      // 128*128
    unsigned short* bt_1l = bt_1h + 128 * 128;
    unsigned short* bt_2h = bt_1l + 128 * 128;
    unsigned short* bt_2l = bt_2h + 128 * 128;
    unsigned short* bt_ch = bt_2l + 128 * 128;                      // 64*128
    unsigned short* bt_cl = bt_ch + 64 * 128;
    int*   cnt_in     = (int*)(bt_cl + 64 * 128);                   // N
    int*   row_start  = cnt_in + NN;                                // N (within-block excl)
    float* rs_out     = (float*)(row_start + NN);                   // N
    float* rs_in      = rs_out + NN;                                // N
    int*   block_sums = (int*)(rs_in + NN);                         // 256
    unsigned short* p_out = (unsigned short*)(block_sums + 256);    // PSZ u16
    int*   csr_src    = (int*)p_out;                                // E ints (p_out dead before fill)

    const int TB = 256;
    const int NB = (NN + 255) / 256;    // 196
    const dim3 ghist(NRG, CH);          // (8, 96) = 768 blocks; range -> XCD aligned
    // graph prepass (no global atomics)
    hist_both<<<ghist, 256, 0, stream>>>(src, dst, p_out, p_in, E);
    merge_scan<<<NB, 256, 0, stream>>>(p_out, p_in, cnt_in, rs_out, rs_in,
                                       row_start, block_sums, NN);
    scan_sums_prep<<<289, 256, 0, stream>>>(block_sums, NB, Wp, W1, W2, Wc,
                                            bt_ph, bt_pl, bt_1h, bt_1l,
                                            bt_2h, bt_2l, bt_ch, bt_cl);
    fill_csr_part<<<ghist, 256, 0, stream>>>(src, dst, row_start, block_sums, p_in,
                                             csr_src, E, NN);

    const dim3 gg(1, (NN + 63) / 64);   // 782 blocks
    // projection: xbuf = n_feats @ Wp + bp            (fp32 out; p_in dead from here)
    mfma_gemm<0, 128><<<gg, 256, 0, stream>>>(n_feats, bt_ph, bt_pl, bp, nullptr,
                                              xbuf, nullptr, NN, H, F);
    // layer 1 GEMM: hbuf = bf16((xbuf @ W1) * rs_out)
    mfma_gemm<1, 128><<<gg, 256, 0, stream>>>(xbuf, bt_1h, bt_1l, nullptr, rs_out,
                                              nullptr, hbuf, NN, H, H);
    aggregate_bf16<<<(NN + 3) / 4, 256, 0, stream>>>((const uint4*)hbuf, csr_src,
                                                     row_start, block_sums, cnt_in,
                                                     rs_in, b1, xbuf, NN);
    // layer 2
    mfma_gemm<1, 128><<<gg, 256, 0, stream>>>(xbuf, bt_2h, bt_2l, nullptr, rs_out,
                                              nullptr, hbuf, NN, H, H);
    aggregate_bf16<<<(NN + 3) / 4, 256, 0, stream>>>((const uint4*)hbuf, csr_src,
                                                     row_start, block_sums, cnt_in,
                                                     rs_in, b2, xbuf, NN);
    // classifier: out = xbuf @ Wc + bc  (B padded to 64 cols, store-masked to 40)
    mfma_gemm<0, 64><<<gg, 256, 0, stream>>>(xbuf, bt_ch, bt_cl, bc, nullptr,
                                             out, nullptr, NN, C, H);
}